// Round 12
// baseline (1046.535 us; speedup 1.0000x reference)
//
#include <hip/hip_runtime.h>

typedef short short8 __attribute__((ext_vector_type(8)));
typedef float f32x4  __attribute__((ext_vector_type(4)));
typedef unsigned int u32x4 __attribute__((ext_vector_type(4)));
typedef _Float16 f16x2 __attribute__((ext_vector_type(2)));

#define NN 20000
#define NE 60000
#define NB 800
#define NTASK 138
#define EB 128     // edges per keinsum block
#define EPAD 60032 // padded edge count for X_T rows

// bf16 weight buffer offsets (shorts)
#define O_WX0 0
#define O_WH0 131072
#define O_WX1 196608
#define O_WH1 262144
#define O_WX2 327680
#define O_WH2 393216
#define O_WF1 458752
#define O_WF2 573952
#define O_WP  650752
#define NWB   686080

// v_dot2_f32_f16 availability (CDNA packed 2-way f16 dot w/ f32 accum)
#if defined(__has_builtin)
#if __has_builtin(__builtin_amdgcn_fdot2)
#define HAVE_DOT2 1
#else
#define HAVE_DOT2 0
#endif
#else
#define HAVE_DOT2 0
#endif

static __device__ __forceinline__ float sigm(float x) { return 1.f / (1.f + expf(-x)); }

static __device__ __forceinline__ unsigned short f2bf(float x) {
    unsigned u = __float_as_uint(x);
    unsigned r = (u + 0x7fffu + ((u >> 16) & 1u)) >> 16;
    return (unsigned short)r;
}
static __device__ __forceinline__ float bf2f(unsigned short b) {
    return __uint_as_float(((unsigned)b) << 16);
}

// LSTM/head weight encode-decode: f16 when dot2 available, else bf16
#if HAVE_DOT2
static __device__ __forceinline__ unsigned short f2w(float x) {
    _Float16 h = (_Float16)x;
    return __builtin_bit_cast(unsigned short, h);
}
static __device__ __forceinline__ float w2f(unsigned short s) {
    return (float)__builtin_bit_cast(_Float16, s);
}
static __device__ __forceinline__ unsigned int pack2f16(float a, float b) {
    unsigned short lo = __builtin_bit_cast(unsigned short, (_Float16)a);
    unsigned short hi = __builtin_bit_cast(unsigned short, (_Float16)b);
    return ((unsigned)hi << 16) | lo;
}
#define BC2(u) __builtin_bit_cast(f16x2, (unsigned int)(u))
#else
static __device__ __forceinline__ unsigned short f2w(float x) { return f2bf(x); }
static __device__ __forceinline__ float w2f(unsigned short s) { return bf2f(s); }
#endif

// =============== kpre: fused [zero | we2T | seg | fpenc | nodeproj | xprep | wcvt] ===============
__global__ void kpre(float* __restrict__ zbase, int nz4,
                     const float* __restrict__ We2, const float* __restrict__ be2,
                     unsigned short* __restrict__ thi,
                     const int* __restrict__ gid, int* __restrict__ seg,
                     const float* __restrict__ fpv, const float* __restrict__ Wfp,
                     const float* __restrict__ bfpv,
                     const float* __restrict__ bng, const float* __restrict__ bnb,
                     const float* __restrict__ bnm, const float* __restrict__ bnv,
                     float* __restrict__ fpb,
                     const float* __restrict__ nf, const float* __restrict__ Wn,
                     const float* __restrict__ bn, float* __restrict__ hf,
                     unsigned short* __restrict__ hb,
                     const float* __restrict__ ef, const float* __restrict__ We1,
                     const float* __restrict__ be1, float* __restrict__ xt,
                     const float* __restrict__ Wlx0, const float* __restrict__ Wlh0,
                     const float* __restrict__ Wlx1, const float* __restrict__ Wlh1,
                     const float* __restrict__ Wlx2, const float* __restrict__ Wlh2,
                     const float* __restrict__ Wf1, const float* __restrict__ Wf2,
                     const float* __restrict__ Wp, unsigned short* __restrict__ wb,
                     int B0, int B1, int B2, int B3, int B4, int B5) {
    __shared__ float st[64 * 65];       // we2 transpose tile
    __shared__ float sNF[16 * 134];     // nodeproj staging
    __shared__ float sred[128];
    __shared__ float sW[6 * 128];       // xprep We1 staging
    __shared__ float sbv[128];
    const int bid = blockIdx.x, tid = threadIdx.x;
    if (bid < B0) {
        long base = (long)bid * 2048 + tid;
        #pragma unroll
        for (int r = 0; r < 8; ++r) {
            long i = base + r * 256;
            if (i < nz4) reinterpret_cast<f32x4*>(zbase)[i] = f32x4{0.f, 0.f, 0.f, 0.f};
        }
    } else if (bid < B1) {
        int c = bid - B0;
        const float* srcp = (c < 128) ? We2 + (long)c * 4096 : be2;
        for (int idx = tid; idx < 4096; idx += 256) {
            int o = idx & 63, i = idx >> 6;
            st[o * 65 + i] = srcp[idx];
        }
        __syncthreads();
        for (int idx = tid; idx < 4096; idx += 256) {
            int i = idx & 63, o = idx >> 6;
            thi[(long)c * 4096 + idx] = f2bf(st[o * 65 + i]);
        }
    } else if (bid < B2) {
        int b = (bid - B1) * 256 + tid;
        if (b <= NB) {
            int lo = 0, hi = NN;
            while (lo < hi) { int mid = (lo + hi) >> 1; if (gid[mid] < b) lo = mid + 1; else hi = mid; }
            seg[b] = lo;
        }
    } else if (bid < B3) {
        int g = bid - B2;
        int u = tid & 127, half = tid >> 7;
        float acc = half ? 0.f : bfpv[u];
        const float* fr = fpv + (long)g * 1024 + half * 512;
        const float* wr = Wfp + (long)half * 512 * 128;
        for (int k = 0; k < 512; ++k) acc += fr[k] * wr[k * 128 + u];
        if (half) sred[u] = acc;
        __syncthreads();
        if (!half) {
            acc += sred[u];
            float sc = bng[u] / sqrtf(bnv[u] + 1e-5f);
            fpb[(long)g * 128 + u] = fmaxf((acc - bnm[u]) * sc + bnb[u], 0.f);
        }
    } else if (bid < B4) {
        int n0 = (bid - B3) * 16;
        const float* nfb = nf + (long)n0 * 134;
        for (int i = tid; i < 16 * 134; i += 256) sNF[i] = nfb[i];
        __syncthreads();
        int u = tid & 63, jg = tid >> 6;
        float a[4];
        float bv = bn[u];
        #pragma unroll
        for (int jj = 0; jj < 4; ++jj) a[jj] = bv;
        for (int k = 0; k < 134; ++k) {
            float w = Wn[k * 64 + u];
            #pragma unroll
            for (int jj = 0; jj < 4; ++jj) a[jj] += sNF[(jg * 4 + jj) * 134 + k] * w;
        }
        #pragma unroll
        for (int jj = 0; jj < 4; ++jj) {
            long o = (long)(n0 + jg * 4 + jj) * 64 + u;
            float v = fmaxf(a[jj], 0.f);
            hf[o] = v;
            hb[o] = f2bf(v);
        }
    } else if (bid < B5) {
        // xprep: X_T[c][e], column-major in e (coalesced stores)
        for (int i = tid; i < 768; i += 256) sW[i] = We1[i];
        if (tid < 128) sbv[tid] = be1[tid];
        __syncthreads();
        int e = (bid - B4) * 256 + tid;
        if (e < NE) {
            float e0 = ef[(long)e * 6 + 0], e1 = ef[(long)e * 6 + 1], e2 = ef[(long)e * 6 + 2];
            float e3 = ef[(long)e * 6 + 3], e4 = ef[(long)e * 6 + 4], e5 = ef[(long)e * 6 + 5];
            for (int c = 0; c < 128; ++c) {
                float a = sbv[c];
                a += e0 * sW[c];       a += e1 * sW[128 + c]; a += e2 * sW[256 + c];
                a += e3 * sW[384 + c]; a += e4 * sW[512 + c]; a += e5 * sW[640 + c];
                xt[(long)c * EPAD + e] = fmaxf(a, 0.f);
            }
        } else if (e < EPAD) {
            for (int c = 0; c < 128; ++c) xt[(long)c * EPAD + e] = 0.f;
        }
    } else {
        // weight conversion f32 -> f16/bf16; LSTM regions repacked to [K/8][512][8]
        int t0 = (bid - B5) * 2048 + tid;
        #pragma unroll
        for (int r = 0; r < 8; ++r) {
            int i = t0 + r * 256;
            if (i >= NWB) break;
            float v;
            if (i < O_WF1) {
                const float* srcp; int base;
                if (i < O_WH0)      { srcp = Wlx0; base = O_WX0; }
                else if (i < O_WX1) { srcp = Wlh0; base = O_WH0; }
                else if (i < O_WH1) { srcp = Wlx1; base = O_WX1; }
                else if (i < O_WX2) { srcp = Wlh1; base = O_WH1; }
                else if (i < O_WH2) { srcp = Wlx2; base = O_WX2; }
                else                { srcp = Wlh2; base = O_WH2; }
                int il = i - base;
                int kb = il >> 12, g = (il >> 3) & 511, kk = il & 7;
                v = srcp[(kb * 8 + kk) * 512 + g];
            }
            else if (i < O_WF2) v = Wf1[i - O_WF1];
            else if (i < O_WP)  v = Wf2[i - O_WF2];
            else                v = Wp[i - O_WP];
            wb[i] = f2w(v);
        }
    }
}

// =============== keinsum v12 (R7): 128 edges/block, GLOAD after barrier, X_T prefetch ===============
__global__ __launch_bounds__(256) void keinsum(
    const unsigned short* __restrict__ hb,
    const float* __restrict__ hf, const float* __restrict__ Wres,
    const float* __restrict__ xt,
    const unsigned short* __restrict__ thi,
    const int* __restrict__ src, const int* __restrict__ dst,
    float* __restrict__ agg) {
    __shared__ __align__(16) unsigned short sB[3 * 64 * 72];
    __shared__ __align__(16) float sX[3 * EB];
    const int bid = blockIdx.x, tid = threadIdx.x;
    if (bid >= 469) {
        int t = (bid - 469) * 256 + tid;
        int u = t & 63;
        int n0 = (t >> 6) * 8;
        if (n0 >= NN) return;
        float a[8] = {0.f, 0.f, 0.f, 0.f, 0.f, 0.f, 0.f, 0.f};
        for (int k = 0; k < 64; ++k) {
            float w = Wres[k * 64 + u];
            #pragma unroll
            for (int j = 0; j < 8; ++j) a[j] += hf[(long)(n0 + j) * 64 + k] * w;
        }
        #pragma unroll
        for (int j = 0; j < 8; ++j) atomicAdd(&agg[(long)(n0 + j) * 64 + u], a[j]);
        return;
    }
    const int lane = tid & 63, wave = tid >> 6;
    const int m = lane & 15, q = lane >> 4;
    const int eb = bid * EB;
    const int e0 = eb + wave * 32;

    short8 ahi[2][2];
    #pragma unroll
    for (int eg = 0; eg < 2; ++eg) {
        int em = e0 + eg * 16 + m; if (em >= NE) em = NE - 1;
        int sn = src[em];
        ahi[eg][0] = *reinterpret_cast<const short8*>(hb + (long)sn * 64 + q * 8);
        ahi[eg][1] = *reinterpret_cast<const short8*>(hb + (long)sn * 64 + 32 + q * 8);
    }
    float msg[2][4][4];
    #pragma unroll
    for (int eg = 0; eg < 2; ++eg)
        #pragma unroll
        for (int nt = 0; nt < 4; ++nt)
            #pragma unroll
            for (int r = 0; r < 4; ++r) msg[eg][nt][r] = 0.f;

    // named register sets (compile-time only -- rule #20)
    short8 rB0a, rB0b, rB1a, rB1b;
    float rX0, rX1;

    auto GLOAD0 = [&](int c) {
        const unsigned short* bb = thi + (long)c * 4096;
        rB0a = *reinterpret_cast<const short8*>(bb + tid * 8);
        rB0b = *reinterpret_cast<const short8*>(bb + (tid + 256) * 8);
        rX0 = (tid < EB) ? ((c < 128) ? xt[(long)c * EPAD + eb + tid] : 1.f) : 0.f;
    };
    auto GLOAD1 = [&](int c) {
        const unsigned short* bb = thi + (long)c * 4096;
        rB1a = *reinterpret_cast<const short8*>(bb + tid * 8);
        rB1b = *reinterpret_cast<const short8*>(bb + (tid + 256) * 8);
        rX1 = (tid < EB) ? ((c < 128) ? xt[(long)c * EPAD + eb + tid] : 1.f) : 0.f;
    };
    auto DSW0 = [&](int buf) {
        unsigned short* base = &sB[buf * 4608];
        *reinterpret_cast<short8*>(&base[(tid >> 3) * 72 + (tid & 7) * 8]) = rB0a;
        int u = tid + 256;
        *reinterpret_cast<short8*>(&base[(u >> 3) * 72 + (u & 7) * 8]) = rB0b;
        if (tid < EB) sX[buf * EB + tid] = rX0;
    };
    auto DSW1 = [&](int buf) {
        unsigned short* base = &sB[buf * 4608];
        *reinterpret_cast<short8*>(&base[(tid >> 3) * 72 + (tid & 7) * 8]) = rB1a;
        int u = tid + 256;
        *reinterpret_cast<short8*>(&base[(u >> 3) * 72 + (u & 7) * 8]) = rB1b;
        if (tid < EB) sX[buf * EB + tid] = rX1;
    };
    auto CMP = [&](int buf) {
        const unsigned short* base = &sB[buf * 4608];
        f32x4 xw[2];
        #pragma unroll
        for (int eg = 0; eg < 2; ++eg)
            xw[eg] = *reinterpret_cast<const f32x4*>(&sX[buf * EB + wave * 32 + eg * 16 + q * 4]);
        short8 b0[4], b1[4];
        #pragma unroll
        for (int nt = 0; nt < 4; ++nt) {
            const unsigned short* rp = &base[(nt * 16 + m) * 72 + q * 8];
            b0[nt] = *reinterpret_cast<const short8*>(rp);
            b1[nt] = *reinterpret_cast<const short8*>(rp + 32);
        }
        #pragma unroll
        for (int eg = 0; eg < 2; ++eg)
            #pragma unroll
            for (int nt = 0; nt < 4; ++nt) {
                f32x4 z = {0.f, 0.f, 0.f, 0.f};
                z = __builtin_amdgcn_mfma_f32_16x16x32_bf16(ahi[eg][0], b0[nt], z, 0, 0, 0);
                z = __builtin_amdgcn_mfma_f32_16x16x32_bf16(ahi[eg][1], b1[nt], z, 0, 0, 0);
                #pragma unroll
                for (int r = 0; r < 4; ++r) msg[eg][nt][r] += xw[eg][r] * z[r];
            }
    };

    // prologue
    GLOAD0(0);
    DSW0(0);
    GLOAD1(1);
    int c = 0;
    for (; c + 1 < 129; c += 2) {
        int s = c % 3;
        __syncthreads();
        if (c + 2 < 129) GLOAD0(c + 2);
        DSW1((s + 1) % 3);
        CMP(s);
        __syncthreads();
        if (c + 3 < 129) GLOAD1(c + 3);
        if (c + 2 < 129) DSW0((s + 2) % 3);
        CMP((s + 1) % 3);
    }
    if (c < 129) { __syncthreads(); CMP(c % 3); }

    #pragma unroll
    for (int eg = 0; eg < 2; ++eg)
        #pragma unroll
        for (int r = 0; r < 4; ++r) {
            int e = e0 + eg * 16 + q * 4 + r;
            if (e < NE) {
                int d = dst[e];
                #pragma unroll
                for (int nt = 0; nt < 4; ++nt)
                    atomicAdd(&agg[(long)d * 64 + nt * 16 + m], msg[eg][nt][r]);
            }
        }
}

// =============== kgruz: LDS-staged GRU (32 nodes/block) + zero next agg ===============
__global__ void kgruz(const float* __restrict__ agg, const float* __restrict__ h,
                      const float* __restrict__ Wgx, const float* __restrict__ bgx,
                      const float* __restrict__ Wgh, const float* __restrict__ bgh,
                      float* __restrict__ hof, unsigned short* __restrict__ hb,
                      float* __restrict__ aggN) {
    const int bid = blockIdx.x, tid = threadIdx.x;
    if (bid >= 625) {
        long base = (long)(bid - 625) * 2048 + tid;
        #pragma unroll
        for (int r = 0; r < 8; ++r) {
            long i = base + r * 256;
            if (i < 320000) reinterpret_cast<f32x4*>(aggN)[i] = f32x4{0.f, 0.f, 0.f, 0.f};
        }
        return;
    }
    __shared__ float sA[2048], sH[2048];
    const int n0 = bid * 32;
    const float* ab = agg + (long)n0 * 64;
    const float* hrow = h + (long)n0 * 64;
    for (int i = tid; i < 2048; i += 256) { sA[i] = ab[i]; sH[i] = hrow[i]; }
    __syncthreads();
    const int u = tid & 63, jg = tid >> 6;
    float xr[8], xz[8], xn[8], hr[8], hz[8], hn[8];
    float b0 = bgx[u], b1 = bgx[64 + u], b2 = bgx[128 + u];
    float d0 = bgh[u], d1 = bgh[64 + u], d2 = bgh[128 + u];
    #pragma unroll
    for (int j = 0; j < 8; ++j) {
        xr[j] = b0; xz[j] = b1; xn[j] = b2;
        hr[j] = d0; hz[j] = d1; hn[j] = d2;
    }
    for (int k = 0; k < 64; ++k) {
        float w0 = Wgx[k * 192 + u], w1 = Wgx[k * 192 + 64 + u], w2 = Wgx[k * 192 + 128 + u];
        float v0 = Wgh[k * 192 + u], v1 = Wgh[k * 192 + 64 + u], v2 = Wgh[k * 192 + 128 + u];
        #pragma unroll
        for (int j = 0; j < 8; ++j) {
            int n = jg * 8 + j;
            float mk = fmaxf(sA[n * 64 + k], 0.f);
            float hk = sH[n * 64 + k];
            xr[j] += mk * w0; xz[j] += mk * w1; xn[j] += mk * w2;
            hr[j] += hk * v0; hz[j] += hk * v1; hn[j] += hk * v2;
        }
    }
    #pragma unroll
    for (int j = 0; j < 8; ++j) {
        int n = jg * 8 + j;
        float rg = sigm(xr[j] + hr[j]);
        float zg = sigm(xz[j] + hz[j]);
        float ng = tanhf(xn[j] + rg * hn[j]);
        long o = (long)(n0 + n) * 64 + u;
        float hv = (1.f - zg) * ng + zg * sH[n * 64 + u];
        hof[o] = hv;
        hb[o] = f2bf(hv);
    }
}

// =============== readout scatter: feat[dst] += [h[src] | relu(ef@Wep+bep)] ===============
__global__ void kreadout(const float* __restrict__ h,
                         const float* __restrict__ ef, const float* __restrict__ Wep,
                         const float* __restrict__ bep,
                         const int* __restrict__ src, const int* __restrict__ dst,
                         float* __restrict__ feat) {
    int t = blockIdx.x * blockDim.x + threadIdx.x;
    if (t >= NE * 128) return;
    int e = t >> 7, j = t & 127;
    float v;
    if (j < 64) {
        v = h[(long)src[e] * 64 + j];
    } else {
        int o = j - 64;
        v = bep[o];
        #pragma unroll
        for (int k = 0; k < 6; ++k) v += ef[(long)e * 6 + k] * Wep[k * 64 + o];
        v = fmaxf(v, 0.f);
    }
    atomicAdd(&feat[(long)dst[e] * 128 + j], v);
}

// =============== klstmattn v7: fused 6 iters, 1 graph/block (800 blocks) ===============
// R10 showed latency/imbalance-bound (VALU 26%, occ 16.6% falling): double block
// concurrency and halve the imbalance tail. Thread = gate, 4 independent dot2 chains,
// unroll 8 (deep load pipeline). Weight traffic 2x but still < L2 BW.
__global__ __launch_bounds__(512) void klstmattn(
    const float* __restrict__ feat, const int* __restrict__ seg,
    float* __restrict__ esg,
    const unsigned short* __restrict__ wb,
    const float* __restrict__ bl0, const float* __restrict__ bl1, const float* __restrict__ bl2,
    const float* __restrict__ fpb,
    const float* __restrict__ bf1, const float* __restrict__ bf2, const float* __restrict__ bp,
    float* __restrict__ out) {
    __shared__ float sQ[256];       // q_star (persistent)
    __shared__ float sHs[3][128];   // LSTM h state per layer
    __shared__ float sCs[3][128];   // LSTM c state per layer
    __shared__ float sG[512];       // gates
    __shared__ float sE[512];       // attention scores/exp; comb(384) in head
    __shared__ float sH2[128];      // layer-2 h (q)
    __shared__ float sR[4][128];    // racc partials
    __shared__ float sred[8];
    __shared__ float s1b[300];
    __shared__ float s2[256];
#if HAVE_DOT2
    __shared__ __align__(16) unsigned int sXp[128];  // packed f16 layer-input x
    __shared__ __align__(16) unsigned int sHp[64];   // packed f16 recurrent h_in
#else
    __shared__ float sXH[256];      // layer input x (f32 fallback)
    __shared__ float sHin[128];     // recurrent h_in (f32 fallback)
#endif
    const int tid = threadIdx.x;
    const int g0 = blockIdx.x;
    const unsigned short* Wx[3] = {wb + O_WX0, wb + O_WX1, wb + O_WX2};
    const unsigned short* Wh[3] = {wb + O_WH0, wb + O_WH1, wb + O_WH2};
    const float* bl[3] = {bl0, bl1, bl2};

    const int wv = tid >> 6, lane = tid & 63;
    const int j = tid & 127, q4 = tid >> 7;   // q4 in 0..3
    const int s0 = seg[g0], s1 = seg[g0 + 1], len = s1 - s0;

    // zero-init persistent state
    if (tid < 256) sQ[tid] = 0.f;
    {
        float* hp = &sHs[0][0];
        float* cp = &sCs[0][0];
        if (tid < 384) { hp[tid] = 0.f; cp[tid] = 0.f; }
    }
    __syncthreads();

    for (int t6 = 0; t6 < 6; ++t6) {
        // stage x (q_star) and layer-0 h_in
#if HAVE_DOT2
        if (tid < 128) {
            sXp[tid] = pack2f16(sQ[2 * tid], sQ[2 * tid + 1]);
        } else if (tid < 192) {
            int uu = tid - 128;
            sHp[uu] = pack2f16(sHs[0][2 * uu], sHs[0][2 * uu + 1]);
        }
#else
        if (tid < 256) sXH[tid] = sQ[tid];
        else if (tid < 384) sHin[tid - 256] = sHs[0][tid - 256];
#endif
        __syncthreads();

        // ---- 3-layer LSTM: thread = gate (512 gates), 1 graph ----
        for (int l = 0; l < 3; ++l) {
            const int Kx = l ? 128 : 256;
            const int g = tid;
            const unsigned short* wxp = Wx[l];
            const unsigned short* whp = Wh[l];
            float a0 = bl[l][g], a1 = 0.f, a2 = 0.f, a3 = 0.f;
#if HAVE_DOT2
            #pragma unroll 8
            for (int kb = 0; kb < (Kx >> 3); ++kb) {
                u32x4 wu = *reinterpret_cast<const u32x4*>(wxp + ((kb << 9) + g) * 8);
                u32x4 x0 = *reinterpret_cast<const u32x4*>(&sXp[kb << 2]);
                a0 = __builtin_amdgcn_fdot2(BC2(wu[0]), BC2(x0[0]), a0, false);
                a1 = __builtin_amdgcn_fdot2(BC2(wu[1]), BC2(x0[1]), a1, false);
                a2 = __builtin_amdgcn_fdot2(BC2(wu[2]), BC2(x0[2]), a2, false);
                a3 = __builtin_amdgcn_fdot2(BC2(wu[3]), BC2(x0[3]), a3, false);
            }
            #pragma unroll 8
            for (int kb = 0; kb < 16; ++kb) {
                u32x4 wu = *reinterpret_cast<const u32x4*>(whp + ((kb << 9) + g) * 8);
                u32x4 h0 = *reinterpret_cast<const u32x4*>(&sHp[kb << 2]);
                a0 = __builtin_amdgcn_fdot2(BC2(wu[0]), BC2(h0[0]), a0, false);
                a1 = __builtin_amdgcn_fdot2(BC2(wu[1]), BC2(h0[1]), a1, false);
                a2 = __builtin_amdgcn_fdot2(BC2(wu[2]), BC2(h0[2]), a2, false);
                a3 = __builtin_amdgcn_fdot2(BC2(wu[3]), BC2(h0[3]), a3, false);
            }
#else
            #pragma unroll 8
            for (int kb = 0; kb < (Kx >> 3); ++kb) {
                short8 wvv = *reinterpret_cast<const short8*>(wxp + ((kb << 9) + g) * 8);
                const f32x4* xp0 = reinterpret_cast<const f32x4*>(&sXH[kb << 3]);
                f32x4 xa = xp0[0], xb = xp0[1];
                #pragma unroll
                for (int kk = 0; kk < 4; ++kk) {
                    a0 += xa[kk] * w2f((unsigned short)wvv[kk]);
                    a1 += xb[kk] * w2f((unsigned short)wvv[kk + 4]);
                }
            }
            #pragma unroll 8
            for (int kb = 0; kb < 16; ++kb) {
                short8 wvv = *reinterpret_cast<const short8*>(whp + ((kb << 9) + g) * 8);
                const f32x4* hp0 = reinterpret_cast<const f32x4*>(&sHin[kb << 3]);
                f32x4 ha = hp0[0], hbv = hp0[1];
                #pragma unroll
                for (int kk = 0; kk < 4; ++kk) {
                    a0 += ha[kk] * w2f((unsigned short)wvv[kk]);
                    a1 += hbv[kk] * w2f((unsigned short)wvv[kk + 4]);
                }
            }
#endif
            sG[g] = (a0 + a1) + (a2 + a3);
            __syncthreads();
            if (tid < 128) {
                int u = tid;
                float gi = sG[u], gf = sG[128 + u], gg = sG[256 + u], go = sG[384 + u];
                float c_ = sigm(gf) * sCs[l][u] + sigm(gi) * tanhf(gg);
                float h_ = sigm(go) * tanhf(c_);
                sCs[l][u] = c_;
                sHs[l][u] = h_;
                if (l == 2) sH2[u] = h_;
#if HAVE_DOT2
                float hn = __shfl_down(h_, 1, 64);
                if (!(u & 1)) sXp[u >> 1] = pack2f16(h_, hn);
#else
                sXH[u] = h_;
#endif
            } else if (l < 2) {
#if HAVE_DOT2
                if (tid < 192) {
                    int uu = tid - 128;
                    sHp[uu] = pack2f16(sHs[l + 1][2 * uu], sHs[l + 1][2 * uu + 1]);
                }
#else
                if (tid < 256) sHin[tid - 128] = sHs[l + 1][tid - 128];
#endif
            }
            __syncthreads();
        }

        // ---- attention (512 threads, 8 waves, one graph) ----
        for (int idx = wv; idx < len; idx += 8) {
            long n = s0 + idx;
            float p = feat[n * 128 + lane] * sH2[lane]
                    + feat[n * 128 + 64 + lane] * sH2[64 + lane];
            for (int off = 32; off; off >>= 1) p += __shfl_down(p, off, 64);
            if (lane == 0) { if (idx < 512) sE[idx] = p; else esg[n] = p; }
        }
        __syncthreads();
        auto ev = [&](int i) { return i < 512 ? sE[i] : esg[s0 + i]; };
        float lm = -1e30f;
        for (int i = tid; i < len; i += 512) lm = fmaxf(lm, ev(i));
        for (int off = 32; off; off >>= 1) lm = fmaxf(lm, __shfl_down(lm, off, 64));
        if (lane == 0) sred[wv] = lm;
        __syncthreads();
        float mx = fmaxf(fmaxf(fmaxf(sred[0], sred[1]), fmaxf(sred[2], sred[3])),
                         fmaxf(fmaxf(sred[4], sred[5]), fmaxf(sred[6], sred[7])));
        __syncthreads();
        float ls = 0.f;
        for (int i = tid; i < len; i += 512) {
            float e_ = expf(ev(i) - mx);
            if (i < 512) sE[i] = e_; else esg[s0 + i] = e_;
            ls += e_;
        }
        for (int off = 32; off; off >>= 1) ls += __shfl_down(ls, off, 64);
        if (lane == 0) sred[wv] = ls;
        __syncthreads();
        float inv = 1.f / (((sred[0] + sred[1]) + (sred[2] + sred[3]))
                         + ((sred[4] + sred[5]) + (sred[6] + sred[7])) + 1e-9f);
        // racc: 4-way i-split x 128 j, 2 accumulators each
        float r0 = 0.f, r1 = 0.f;
        {
            int i = q4;
            for (; i + 4 < len; i += 8) {
                r0 += ev(i) * feat[(long)(s0 + i) * 128 + j];
                r1 += ev(i + 4) * feat[(long)(s0 + i + 4) * 128 + j];
            }
            for (; i < len; i += 4)
                r0 += ev(i) * feat[(long)(s0 + i) * 128 + j];
        }
        sR[q4][j] = r0 + r1;
        __syncthreads();
        float rr = ((sR[0][j] + sR[1][j]) + (sR[2][j] + sR[3][j])) * inv;
        if (q4 == 0) {
            sQ[j] = sH2[j];          // q
            sQ[128 + j] = rr;        // r
        }

        if (t6 == 5) {
            __syncthreads();
            // ---- FFN head: comb(384) -> 300 -> 256 -> NTASK ----
            if (q4 == 0)      sE[j] = sH2[j];
            else if (q4 == 1) sE[128 + j] = rr;
            else if (q4 == 2) sE[256 + j] = fpb[(long)g0 * 128 + j];
            __syncthreads();
            const unsigned short* Wf1b = wb + O_WF1;
            const unsigned short* Wf2b = wb + O_WF2;
            const unsigned short* Wpb  = wb + O_WP;
            for (int u = tid; u < 300; u += 512) {
                float acc = bf1[u];
                for (int k = 0; k < 384; ++k) acc += sE[k] * w2f(Wf1b[k * 300 + u]);
                s1b[u] = fmaxf(acc, 0.f);
            }
            __syncthreads();
            for (int u = tid; u < 256; u += 512) {
                float acc = bf2[u];
                for (int k = 0; k < 300; ++k) acc += s1b[k] * w2f(Wf2b[k * 256 + u]);
                s2[u] = fmaxf(acc, 0.f);
            }
            __syncthreads();
            for (int u = tid; u < NTASK; u += 512) {
                float acc = bp[u];
                for (int k = 0; k < 256; ++k) acc += s2[k] * w2f(Wpb[k * NTASK + u]);
                out[(long)g0 * NTASK + u] = acc;
            }
        } else {
            __syncthreads();   // protect sQ/sE reuse before next iteration
        }
    }
}

extern "C" void kernel_launch(void* const* d_in, const int* in_sizes, int n_in,
                              void* d_out, int out_size, void* d_ws, size_t ws_size,
                              hipStream_t stream) {
    auto fp_ = [&](int i) { return (const float*)d_in[i]; };
    auto ip_ = [&](int i) { return (const int*)d_in[i]; };
    const float *nf = fp_(0), *ef = fp_(1), *fpv = fp_(2);
    const int *src = ip_(3), *dst = ip_(4), *gid = ip_(5);
    const float *Wn = fp_(6), *bn = fp_(7), *We1 = fp_(8), *be1 = fp_(9);
    const float *We2 = fp_(10), *be2 = fp_(11), *Wres = fp_(12);
    const float *Wgx = fp_(13), *bgx = fp_(14), *Wgh = fp_(15), *bgh = fp_(16);
    const float *Wep = fp_(17), *bep = fp_(18);
    const float *Wlx0 = fp_(19), *Wlh0 = fp_(20), *bl0 = fp_(21);
    const float *Wlx1 = fp_(22), *Wlh1 = fp_(23), *bl1 = fp_(24);
    const float *Wlx2 = fp_(25), *Wlh2 = fp_(26), *bl2 = fp_(27);
    const float *Wfp = fp_(28), *bfpv = fp_(29);
    const float *bng = fp_(30), *bnb = fp_(31), *bnm = fp_(32), *bnv = fp_(33);
    const float *Wf1 = fp_(34), *bf1 = fp_(35), *Wf2 = fp_(36), *bf2 = fp_(37);
    const float *Wp = fp_(38), *bp = fp_(39);

    char* w = (char*)d_ws;
    auto alloc = [&](size_t bytes) -> char* {
        char* p = w; w += (bytes + 255) & ~(size_t)255; return p;
    };
    float* hA = (float*)alloc((size_t)NN * 64 * 4);
    float* hB = (float*)alloc((size_t)NN * 64 * 4);
    unsigned short* hbA = (unsigned short*)alloc((size_t)NN * 64 * 2);
    unsigned short* hbB = (unsigned short*)alloc((size_t)NN * 64 * 2);
    unsigned short* we2thi = (unsigned short*)alloc((size_t)129 * 4096 * 2);
    unsigned short* wbf = (unsigned short*)alloc((size_t)NWB * 2);
    float* aggB = (float*)alloc((size_t)NN * 64 * 4);   // zeroed by kgruz
    char* zstart = w;                               // ---- zeroed region start ----
    float* aggA  = (float*)alloc((size_t)NN * 64 * 4);
    float* feat  = (float*)alloc((size_t)NN * 128 * 4);
    size_t zfloats = (size_t)(w - zstart) / 4;      // ---- zeroed region end ----
    float* es   = (float*)alloc((size_t)NN * 4);
    int*   seg  = (int*)alloc((size_t)(NB + 1) * 4);
    float* fpb  = (float*)alloc((size_t)NB * 128 * 4);
    float* xt   = (float*)alloc((size_t)128 * EPAD * 4);   // X_T edge-net activations

    // --- kpre section boundaries ---
    int nz4 = (int)(zfloats / 4);
    int zb  = (nz4 + 2047) / 2048;
    int B0 = zb;
    int B1 = B0 + 129;            // we2T: 1 block/chunk
    int B2 = B1 + 4;              // seg
    int B3 = B2 + NB;             // fpenc: 1 block/graph
    int B4 = B3 + 1250;           // nodeproj: 16 nodes/block
    int B5 = B4 + 235;            // xprep: 256 edges/block
    int B6 = B5 + (NWB + 2047) / 2048;  // weight conversion
    kpre<<<B6, 256, 0, stream>>>((float*)zstart, nz4, We2, be2, we2thi, gid, seg,
                                 fpv, Wfp, bfpv, bng, bnb, bnm, bnv, fpb,
                                 nf, Wn, bn, hA, hbA,
                                 ef, We1, be1, xt,
                                 Wlx0, Wlh0, Wlx1, Wlh1, Wlx2, Wlh2, Wf1, Wf2, Wp, wbf,
                                 B0, B1, B2, B3, B4, B5);

    float* hf[2] = {hA, hB};
    unsigned short* hb[2] = {hbA, hbB};
    float* aggbuf[2] = {aggA, aggB};
    int cur = 0;
    for (int it = 0; it < 3; ++it) {
        float* agg  = aggbuf[it & 1];
        float* aggN = aggbuf[1 - (it & 1)];
        keinsum<<<469 + 625, 256, 0, stream>>>(hb[cur], hf[cur], Wres,
                                               xt, we2thi, src, dst, agg);
        kgruz<<<625 + 157, 256, 0, stream>>>(agg, hf[cur], Wgx, bgx, Wgh, bgh,
                                             hf[1 - cur], hb[1 - cur], aggN);
        cur = 1 - cur;
    }
    kreadout<<<(NE * 128 + 255) / 256, 256, 0, stream>>>(hf[cur], ef, Wep, bep, src, dst, feat);

    klstmattn<<<NB, 512, 0, stream>>>(feat, seg, es, wbf, bl0, bl1, bl2,
                                      fpb, bf1, bf2, bp, (float*)d_out);
}

// Round 13
// 825.199 us; speedup vs baseline: 1.2682x; 1.2682x over previous
//
#include <hip/hip_runtime.h>

typedef short short8 __attribute__((ext_vector_type(8)));
typedef float f32x4  __attribute__((ext_vector_type(4)));
typedef unsigned int u32x4 __attribute__((ext_vector_type(4)));
typedef _Float16 f16x2 __attribute__((ext_vector_type(2)));

#define NN 20000
#define NE 60000
#define NB 800
#define NTASK 138
#define EB 128     // edges per keinsum block
#define EPAD 60032 // padded edge count for X_T rows
#define CF 32      // cached feat rows per graph in klstmattn

// bf16 weight buffer offsets (shorts)
#define O_WX0 0
#define O_WH0 131072
#define O_WX1 196608
#define O_WH1 262144
#define O_WX2 327680
#define O_WH2 393216
#define O_WF1 458752
#define O_WF2 573952
#define O_WP  650752
#define NWB   686080

// v_dot2_f32_f16 availability (CDNA packed 2-way f16 dot w/ f32 accum)
#if defined(__has_builtin)
#if __has_builtin(__builtin_amdgcn_fdot2)
#define HAVE_DOT2 1
#else
#define HAVE_DOT2 0
#endif
#else
#define HAVE_DOT2 0
#endif

static __device__ __forceinline__ float sigm(float x) { return 1.f / (1.f + expf(-x)); }

static __device__ __forceinline__ unsigned short f2bf(float x) {
    unsigned u = __float_as_uint(x);
    unsigned r = (u + 0x7fffu + ((u >> 16) & 1u)) >> 16;
    return (unsigned short)r;
}
static __device__ __forceinline__ float bf2f(unsigned short b) {
    return __uint_as_float(((unsigned)b) << 16);
}

// LSTM/head weight encode-decode: f16 when dot2 available, else bf16
#if HAVE_DOT2
static __device__ __forceinline__ unsigned short f2w(float x) {
    _Float16 h = (_Float16)x;
    return __builtin_bit_cast(unsigned short, h);
}
static __device__ __forceinline__ float w2f(unsigned short s) {
    return (float)__builtin_bit_cast(_Float16, s);
}
static __device__ __forceinline__ unsigned int pack2f16(float a, float b) {
    unsigned short lo = __builtin_bit_cast(unsigned short, (_Float16)a);
    unsigned short hi = __builtin_bit_cast(unsigned short, (_Float16)b);
    return ((unsigned)hi << 16) | lo;
}
#define BC2(u) __builtin_bit_cast(f16x2, (unsigned int)(u))
#else
static __device__ __forceinline__ unsigned short f2w(float x) { return f2bf(x); }
static __device__ __forceinline__ float w2f(unsigned short s) { return bf2f(s); }
#endif

// =============== kpre: fused [zero | we2T | seg | fpenc | nodeproj | xprep | wcvt] ===============
__global__ void kpre(float* __restrict__ zbase, int nz4,
                     const float* __restrict__ We2, const float* __restrict__ be2,
                     unsigned short* __restrict__ thi,
                     const int* __restrict__ gid, int* __restrict__ seg,
                     const float* __restrict__ fpv, const float* __restrict__ Wfp,
                     const float* __restrict__ bfpv,
                     const float* __restrict__ bng, const float* __restrict__ bnb,
                     const float* __restrict__ bnm, const float* __restrict__ bnv,
                     float* __restrict__ fpb,
                     const float* __restrict__ nf, const float* __restrict__ Wn,
                     const float* __restrict__ bn, float* __restrict__ hf,
                     unsigned short* __restrict__ hb,
                     const float* __restrict__ ef, const float* __restrict__ We1,
                     const float* __restrict__ be1, float* __restrict__ xt,
                     const float* __restrict__ Wlx0, const float* __restrict__ Wlh0,
                     const float* __restrict__ Wlx1, const float* __restrict__ Wlh1,
                     const float* __restrict__ Wlx2, const float* __restrict__ Wlh2,
                     const float* __restrict__ Wf1, const float* __restrict__ Wf2,
                     const float* __restrict__ Wp, unsigned short* __restrict__ wb,
                     int B0, int B1, int B2, int B3, int B4, int B5) {
    __shared__ float st[64 * 65];       // we2 transpose tile
    __shared__ float sNF[16 * 134];     // nodeproj staging
    __shared__ float sred[128];
    __shared__ float sW[6 * 128];       // xprep We1 staging
    __shared__ float sbv[128];
    const int bid = blockIdx.x, tid = threadIdx.x;
    if (bid < B0) {
        long base = (long)bid * 2048 + tid;
        #pragma unroll
        for (int r = 0; r < 8; ++r) {
            long i = base + r * 256;
            if (i < nz4) reinterpret_cast<f32x4*>(zbase)[i] = f32x4{0.f, 0.f, 0.f, 0.f};
        }
    } else if (bid < B1) {
        int c = bid - B0;
        const float* srcp = (c < 128) ? We2 + (long)c * 4096 : be2;
        for (int idx = tid; idx < 4096; idx += 256) {
            int o = idx & 63, i = idx >> 6;
            st[o * 65 + i] = srcp[idx];
        }
        __syncthreads();
        for (int idx = tid; idx < 4096; idx += 256) {
            int i = idx & 63, o = idx >> 6;
            thi[(long)c * 4096 + idx] = f2bf(st[o * 65 + i]);
        }
    } else if (bid < B2) {
        int b = (bid - B1) * 256 + tid;
        if (b <= NB) {
            int lo = 0, hi = NN;
            while (lo < hi) { int mid = (lo + hi) >> 1; if (gid[mid] < b) lo = mid + 1; else hi = mid; }
            seg[b] = lo;
        }
    } else if (bid < B3) {
        int g = bid - B2;
        int u = tid & 127, half = tid >> 7;
        float acc = half ? 0.f : bfpv[u];
        const float* fr = fpv + (long)g * 1024 + half * 512;
        const float* wr = Wfp + (long)half * 512 * 128;
        for (int k = 0; k < 512; ++k) acc += fr[k] * wr[k * 128 + u];
        if (half) sred[u] = acc;
        __syncthreads();
        if (!half) {
            acc += sred[u];
            float sc = bng[u] / sqrtf(bnv[u] + 1e-5f);
            fpb[(long)g * 128 + u] = fmaxf((acc - bnm[u]) * sc + bnb[u], 0.f);
        }
    } else if (bid < B4) {
        int n0 = (bid - B3) * 16;
        const float* nfb = nf + (long)n0 * 134;
        for (int i = tid; i < 16 * 134; i += 256) sNF[i] = nfb[i];
        __syncthreads();
        int u = tid & 63, jg = tid >> 6;
        float a[4];
        float bv = bn[u];
        #pragma unroll
        for (int jj = 0; jj < 4; ++jj) a[jj] = bv;
        for (int k = 0; k < 134; ++k) {
            float w = Wn[k * 64 + u];
            #pragma unroll
            for (int jj = 0; jj < 4; ++jj) a[jj] += sNF[(jg * 4 + jj) * 134 + k] * w;
        }
        #pragma unroll
        for (int jj = 0; jj < 4; ++jj) {
            long o = (long)(n0 + jg * 4 + jj) * 64 + u;
            float v = fmaxf(a[jj], 0.f);
            hf[o] = v;
            hb[o] = f2bf(v);
        }
    } else if (bid < B5) {
        // xprep: X_T[c][e], column-major in e (coalesced stores)
        for (int i = tid; i < 768; i += 256) sW[i] = We1[i];
        if (tid < 128) sbv[tid] = be1[tid];
        __syncthreads();
        int e = (bid - B4) * 256 + tid;
        if (e < NE) {
            float e0 = ef[(long)e * 6 + 0], e1 = ef[(long)e * 6 + 1], e2 = ef[(long)e * 6 + 2];
            float e3 = ef[(long)e * 6 + 3], e4 = ef[(long)e * 6 + 4], e5 = ef[(long)e * 6 + 5];
            for (int c = 0; c < 128; ++c) {
                float a = sbv[c];
                a += e0 * sW[c];       a += e1 * sW[128 + c]; a += e2 * sW[256 + c];
                a += e3 * sW[384 + c]; a += e4 * sW[512 + c]; a += e5 * sW[640 + c];
                xt[(long)c * EPAD + e] = fmaxf(a, 0.f);
            }
        } else if (e < EPAD) {
            for (int c = 0; c < 128; ++c) xt[(long)c * EPAD + e] = 0.f;
        }
    } else {
        // weight conversion f32 -> f16/bf16; LSTM regions repacked to [K/8][512][8]
        int t0 = (bid - B5) * 2048 + tid;
        #pragma unroll
        for (int r = 0; r < 8; ++r) {
            int i = t0 + r * 256;
            if (i >= NWB) break;
            float v;
            if (i < O_WF1) {
                const float* srcp; int base;
                if (i < O_WH0)      { srcp = Wlx0; base = O_WX0; }
                else if (i < O_WX1) { srcp = Wlh0; base = O_WH0; }
                else if (i < O_WH1) { srcp = Wlx1; base = O_WX1; }
                else if (i < O_WX2) { srcp = Wlh1; base = O_WH1; }
                else if (i < O_WH2) { srcp = Wlx2; base = O_WX2; }
                else                { srcp = Wlh2; base = O_WH2; }
                int il = i - base;
                int kb = il >> 12, g = (il >> 3) & 511, kk = il & 7;
                v = srcp[(kb * 8 + kk) * 512 + g];
            }
            else if (i < O_WF2) v = Wf1[i - O_WF1];
            else if (i < O_WP)  v = Wf2[i - O_WF2];
            else                v = Wp[i - O_WP];
            wb[i] = f2w(v);
        }
    }
}

// =============== keinsum v12 (R7): 128 edges/block, GLOAD after barrier, X_T prefetch ===============
__global__ __launch_bounds__(256) void keinsum(
    const unsigned short* __restrict__ hb,
    const float* __restrict__ hf, const float* __restrict__ Wres,
    const float* __restrict__ xt,
    const unsigned short* __restrict__ thi,
    const int* __restrict__ src, const int* __restrict__ dst,
    float* __restrict__ agg) {
    __shared__ __align__(16) unsigned short sB[3 * 64 * 72];
    __shared__ __align__(16) float sX[3 * EB];
    const int bid = blockIdx.x, tid = threadIdx.x;
    if (bid >= 469) {
        int t = (bid - 469) * 256 + tid;
        int u = t & 63;
        int n0 = (t >> 6) * 8;
        if (n0 >= NN) return;
        float a[8] = {0.f, 0.f, 0.f, 0.f, 0.f, 0.f, 0.f, 0.f};
        for (int k = 0; k < 64; ++k) {
            float w = Wres[k * 64 + u];
            #pragma unroll
            for (int j = 0; j < 8; ++j) a[j] += hf[(long)(n0 + j) * 64 + k] * w;
        }
        #pragma unroll
        for (int j = 0; j < 8; ++j) atomicAdd(&agg[(long)(n0 + j) * 64 + u], a[j]);
        return;
    }
    const int lane = tid & 63, wave = tid >> 6;
    const int m = lane & 15, q = lane >> 4;
    const int eb = bid * EB;
    const int e0 = eb + wave * 32;

    short8 ahi[2][2];
    #pragma unroll
    for (int eg = 0; eg < 2; ++eg) {
        int em = e0 + eg * 16 + m; if (em >= NE) em = NE - 1;
        int sn = src[em];
        ahi[eg][0] = *reinterpret_cast<const short8*>(hb + (long)sn * 64 + q * 8);
        ahi[eg][1] = *reinterpret_cast<const short8*>(hb + (long)sn * 64 + 32 + q * 8);
    }
    float msg[2][4][4];
    #pragma unroll
    for (int eg = 0; eg < 2; ++eg)
        #pragma unroll
        for (int nt = 0; nt < 4; ++nt)
            #pragma unroll
            for (int r = 0; r < 4; ++r) msg[eg][nt][r] = 0.f;

    // named register sets (compile-time only -- rule #20)
    short8 rB0a, rB0b, rB1a, rB1b;
    float rX0, rX1;

    auto GLOAD0 = [&](int c) {
        const unsigned short* bb = thi + (long)c * 4096;
        rB0a = *reinterpret_cast<const short8*>(bb + tid * 8);
        rB0b = *reinterpret_cast<const short8*>(bb + (tid + 256) * 8);
        rX0 = (tid < EB) ? ((c < 128) ? xt[(long)c * EPAD + eb + tid] : 1.f) : 0.f;
    };
    auto GLOAD1 = [&](int c) {
        const unsigned short* bb = thi + (long)c * 4096;
        rB1a = *reinterpret_cast<const short8*>(bb + tid * 8);
        rB1b = *reinterpret_cast<const short8*>(bb + (tid + 256) * 8);
        rX1 = (tid < EB) ? ((c < 128) ? xt[(long)c * EPAD + eb + tid] : 1.f) : 0.f;
    };
    auto DSW0 = [&](int buf) {
        unsigned short* base = &sB[buf * 4608];
        *reinterpret_cast<short8*>(&base[(tid >> 3) * 72 + (tid & 7) * 8]) = rB0a;
        int u = tid + 256;
        *reinterpret_cast<short8*>(&base[(u >> 3) * 72 + (u & 7) * 8]) = rB0b;
        if (tid < EB) sX[buf * EB + tid] = rX0;
    };
    auto DSW1 = [&](int buf) {
        unsigned short* base = &sB[buf * 4608];
        *reinterpret_cast<short8*>(&base[(tid >> 3) * 72 + (tid & 7) * 8]) = rB1a;
        int u = tid + 256;
        *reinterpret_cast<short8*>(&base[(u >> 3) * 72 + (u & 7) * 8]) = rB1b;
        if (tid < EB) sX[buf * EB + tid] = rX1;
    };
    auto CMP = [&](int buf) {
        const unsigned short* base = &sB[buf * 4608];
        f32x4 xw[2];
        #pragma unroll
        for (int eg = 0; eg < 2; ++eg)
            xw[eg] = *reinterpret_cast<const f32x4*>(&sX[buf * EB + wave * 32 + eg * 16 + q * 4]);
        short8 b0[4], b1[4];
        #pragma unroll
        for (int nt = 0; nt < 4; ++nt) {
            const unsigned short* rp = &base[(nt * 16 + m) * 72 + q * 8];
            b0[nt] = *reinterpret_cast<const short8*>(rp);
            b1[nt] = *reinterpret_cast<const short8*>(rp + 32);
        }
        #pragma unroll
        for (int eg = 0; eg < 2; ++eg)
            #pragma unroll
            for (int nt = 0; nt < 4; ++nt) {
                f32x4 z = {0.f, 0.f, 0.f, 0.f};
                z = __builtin_amdgcn_mfma_f32_16x16x32_bf16(ahi[eg][0], b0[nt], z, 0, 0, 0);
                z = __builtin_amdgcn_mfma_f32_16x16x32_bf16(ahi[eg][1], b1[nt], z, 0, 0, 0);
                #pragma unroll
                for (int r = 0; r < 4; ++r) msg[eg][nt][r] += xw[eg][r] * z[r];
            }
    };

    // prologue
    GLOAD0(0);
    DSW0(0);
    GLOAD1(1);
    int c = 0;
    for (; c + 1 < 129; c += 2) {
        int s = c % 3;
        __syncthreads();
        if (c + 2 < 129) GLOAD0(c + 2);
        DSW1((s + 1) % 3);
        CMP(s);
        __syncthreads();
        if (c + 3 < 129) GLOAD1(c + 3);
        if (c + 2 < 129) DSW0((s + 2) % 3);
        CMP((s + 1) % 3);
    }
    if (c < 129) { __syncthreads(); CMP(c % 3); }

    #pragma unroll
    for (int eg = 0; eg < 2; ++eg)
        #pragma unroll
        for (int r = 0; r < 4; ++r) {
            int e = e0 + eg * 16 + q * 4 + r;
            if (e < NE) {
                int d = dst[e];
                #pragma unroll
                for (int nt = 0; nt < 4; ++nt)
                    atomicAdd(&agg[(long)d * 64 + nt * 16 + m], msg[eg][nt][r]);
            }
        }
}

// =============== kgruz: LDS-staged GRU (32 nodes/block) + zero next agg ===============
__global__ void kgruz(const float* __restrict__ agg, const float* __restrict__ h,
                      const float* __restrict__ Wgx, const float* __restrict__ bgx,
                      const float* __restrict__ Wgh, const float* __restrict__ bgh,
                      float* __restrict__ hof, unsigned short* __restrict__ hb,
                      float* __restrict__ aggN) {
    const int bid = blockIdx.x, tid = threadIdx.x;
    if (bid >= 625) {
        long base = (long)(bid - 625) * 2048 + tid;
        #pragma unroll
        for (int r = 0; r < 8; ++r) {
            long i = base + r * 256;
            if (i < 320000) reinterpret_cast<f32x4*>(aggN)[i] = f32x4{0.f, 0.f, 0.f, 0.f};
        }
        return;
    }
    __shared__ float sA[2048], sH[2048];
    const int n0 = bid * 32;
    const float* ab = agg + (long)n0 * 64;
    const float* hrow = h + (long)n0 * 64;
    for (int i = tid; i < 2048; i += 256) { sA[i] = ab[i]; sH[i] = hrow[i]; }
    __syncthreads();
    const int u = tid & 63, jg = tid >> 6;
    float xr[8], xz[8], xn[8], hr[8], hz[8], hn[8];
    float b0 = bgx[u], b1 = bgx[64 + u], b2 = bgx[128 + u];
    float d0 = bgh[u], d1 = bgh[64 + u], d2 = bgh[128 + u];
    #pragma unroll
    for (int j = 0; j < 8; ++j) {
        xr[j] = b0; xz[j] = b1; xn[j] = b2;
        hr[j] = d0; hz[j] = d1; hn[j] = d2;
    }
    for (int k = 0; k < 64; ++k) {
        float w0 = Wgx[k * 192 + u], w1 = Wgx[k * 192 + 64 + u], w2 = Wgx[k * 192 + 128 + u];
        float v0 = Wgh[k * 192 + u], v1 = Wgh[k * 192 + 64 + u], v2 = Wgh[k * 192 + 128 + u];
        #pragma unroll
        for (int j = 0; j < 8; ++j) {
            int n = jg * 8 + j;
            float mk = fmaxf(sA[n * 64 + k], 0.f);
            float hk = sH[n * 64 + k];
            xr[j] += mk * w0; xz[j] += mk * w1; xn[j] += mk * w2;
            hr[j] += hk * v0; hz[j] += hk * v1; hn[j] += hk * v2;
        }
    }
    #pragma unroll
    for (int j = 0; j < 8; ++j) {
        int n = jg * 8 + j;
        float rg = sigm(xr[j] + hr[j]);
        float zg = sigm(xz[j] + hz[j]);
        float ng = tanhf(xn[j] + rg * hn[j]);
        long o = (long)(n0 + n) * 64 + u;
        float hv = (1.f - zg) * ng + zg * sH[n * 64 + u];
        hof[o] = hv;
        hb[o] = f2bf(hv);
    }
}

// =============== readout scatter: feat[dst] += [h[src] | relu(ef@Wep+bep)] ===============
__global__ void kreadout(const float* __restrict__ h,
                         const float* __restrict__ ef, const float* __restrict__ Wep,
                         const float* __restrict__ bep,
                         const int* __restrict__ src, const int* __restrict__ dst,
                         float* __restrict__ feat) {
    int t = blockIdx.x * blockDim.x + threadIdx.x;
    if (t >= NE * 128) return;
    int e = t >> 7, j = t & 127;
    float v;
    if (j < 64) {
        v = h[(long)src[e] * 64 + j];
    } else {
        int o = j - 64;
        v = bep[o];
        #pragma unroll
        for (int k = 0; k < 6; ++k) v += ef[(long)e * 6 + k] * Wep[k * 64 + o];
        v = fmaxf(v, 0.f);
    }
    atomicAdd(&feat[(long)dst[e] * 128 + j], v);
}

// =============== klstmattn v8: R10's fused 2-graph/block + feat LDS cache ===============
// R12 falsified 1-graph/block (weight reuse > block concurrency). On top of R10:
// cache first CF=32 rows of each graph's feat segment in LDS (loaded once; segments
// avg 25 rows) -- removes up to 12 latency-bound global passes over feat.
__global__ __launch_bounds__(512) void klstmattn(
    const float* __restrict__ feat, const int* __restrict__ seg,
    float* __restrict__ esg,
    const unsigned short* __restrict__ wb,
    const float* __restrict__ bl0, const float* __restrict__ bl1, const float* __restrict__ bl2,
    const float* __restrict__ fpb,
    const float* __restrict__ bf1, const float* __restrict__ bf2, const float* __restrict__ bp,
    float* __restrict__ out) {
    __shared__ float sQ[2][256];    // q_star (persistent across iterations)
    __shared__ float sHs[3][2][128];// LSTM h state per layer
    __shared__ float sCs[3][2][128];// LSTM c state per layer
    __shared__ float sG[2][512];    // gates
    __shared__ float sE[2][512];    // attention scores/exp; reused as comb(384) in head
    __shared__ float sH2[2][128];   // layer-2 h (q)
    __shared__ float sR[2][2][128]; // racc partials
    __shared__ float sred[2][4];
    __shared__ float s1b[2][300];
    __shared__ float s2[2][256];
    __shared__ float sF[2][CF * 128]; // cached feat rows (iteration-invariant)
#if HAVE_DOT2
    __shared__ __align__(16) unsigned int sXp[2][128];  // packed f16 layer-input x
    __shared__ __align__(16) unsigned int sHp[2][64];   // packed f16 recurrent h_in
#else
    __shared__ float sXH[2][256];   // layer input x (f32 fallback)
    __shared__ float sHin[2][128];  // recurrent h_in (f32 fallback)
#endif
    const int tid = threadIdx.x;
    const int b0g = blockIdx.x * 2;
    const unsigned short* Wx[3] = {wb + O_WX0, wb + O_WX1, wb + O_WX2};
    const unsigned short* Wh[3] = {wb + O_WH0, wb + O_WH1, wb + O_WH2};
    const float* bl[3] = {bl0, bl1, bl2};

    const int group = tid >> 8;         // 0..1 (attention/head indexing)
    const int t = tid & 255;
    const int wv = t >> 6, lane = t & 63;
    const int j = t & 127, half = t >> 7;
    const int s0 = seg[b0g + group], s1 = seg[b0g + group + 1], len = s1 - s0;

    // zero-init persistent state + cache feat rows (one barrier covers all)
    sQ[tid >> 8][tid & 255] = 0.f;
    {
        float* hp = &sHs[0][0][0];
        float* cp = &sCs[0][0][0];
        for (int i = tid; i < 768; i += 512) { hp[i] = 0.f; cp[i] = 0.f; }
    }
    {
        int rows = len < CF ? len : CF;
        for (int i = t; i < rows * 128; i += 256)
            sF[group][i] = feat[(long)(s0 + (i >> 7)) * 128 + (i & 127)];
    }
    __syncthreads();

    for (int t6 = 0; t6 < 6; ++t6) {
        // stage x (q_star) and layer-0 h_in
#if HAVE_DOT2
        if (tid < 256) {
            int b = tid >> 7, u = tid & 127;
            sXp[b][u] = pack2f16(sQ[b][2 * u], sQ[b][2 * u + 1]);
        } else if (tid < 384) {
            int t2 = tid - 256;
            int bb = t2 >> 6, uu = t2 & 63;
            sHp[bb][uu] = pack2f16(sHs[0][bb][2 * uu], sHs[0][bb][2 * uu + 1]);
        }
#else
        {
            int b = tid >> 8, u = tid & 255;
            sXH[b][u] = sQ[b][u];
            if (tid < 256) {
                int bb = tid >> 7, uu = tid & 127;
                sHin[bb][uu] = sHs[0][bb][uu];
            }
        }
#endif
        __syncthreads();

        // ---- 3-layer LSTM ----
        for (int l = 0; l < 3; ++l) {
            const int Kx = l ? 128 : 256;
            const int g = tid;
            const unsigned short* wxp = Wx[l];
            const unsigned short* whp = Wh[l];
            float bv = bl[l][g];
            float a0 = bv, a1 = bv, a0b = 0.f, a1b = 0.f;
#if HAVE_DOT2
            #pragma unroll 4
            for (int kb = 0; kb < (Kx >> 3); ++kb) {
                u32x4 wu = *reinterpret_cast<const u32x4*>(wxp + ((kb << 9) + g) * 8);
                u32x4 x0 = *reinterpret_cast<const u32x4*>(&sXp[0][kb << 2]);
                u32x4 x1 = *reinterpret_cast<const u32x4*>(&sXp[1][kb << 2]);
                a0  = __builtin_amdgcn_fdot2(BC2(wu[0]), BC2(x0[0]), a0,  false);
                a1  = __builtin_amdgcn_fdot2(BC2(wu[0]), BC2(x1[0]), a1,  false);
                a0b = __builtin_amdgcn_fdot2(BC2(wu[1]), BC2(x0[1]), a0b, false);
                a1b = __builtin_amdgcn_fdot2(BC2(wu[1]), BC2(x1[1]), a1b, false);
                a0  = __builtin_amdgcn_fdot2(BC2(wu[2]), BC2(x0[2]), a0,  false);
                a1  = __builtin_amdgcn_fdot2(BC2(wu[2]), BC2(x1[2]), a1,  false);
                a0b = __builtin_amdgcn_fdot2(BC2(wu[3]), BC2(x0[3]), a0b, false);
                a1b = __builtin_amdgcn_fdot2(BC2(wu[3]), BC2(x1[3]), a1b, false);
            }
            #pragma unroll 4
            for (int kb = 0; kb < 16; ++kb) {
                u32x4 wu = *reinterpret_cast<const u32x4*>(whp + ((kb << 9) + g) * 8);
                u32x4 h0 = *reinterpret_cast<const u32x4*>(&sHp[0][kb << 2]);
                u32x4 h1 = *reinterpret_cast<const u32x4*>(&sHp[1][kb << 2]);
                a0  = __builtin_amdgcn_fdot2(BC2(wu[0]), BC2(h0[0]), a0,  false);
                a1  = __builtin_amdgcn_fdot2(BC2(wu[0]), BC2(h1[0]), a1,  false);
                a0b = __builtin_amdgcn_fdot2(BC2(wu[1]), BC2(h0[1]), a0b, false);
                a1b = __builtin_amdgcn_fdot2(BC2(wu[1]), BC2(h1[1]), a1b, false);
                a0  = __builtin_amdgcn_fdot2(BC2(wu[2]), BC2(h0[2]), a0,  false);
                a1  = __builtin_amdgcn_fdot2(BC2(wu[2]), BC2(h1[2]), a1,  false);
                a0b = __builtin_amdgcn_fdot2(BC2(wu[3]), BC2(h0[3]), a0b, false);
                a1b = __builtin_amdgcn_fdot2(BC2(wu[3]), BC2(h1[3]), a1b, false);
            }
#else
            #pragma unroll 4
            for (int kb = 0; kb < (Kx >> 3); ++kb) {
                short8 wvv = *reinterpret_cast<const short8*>(wxp + ((kb << 9) + g) * 8);
                const f32x4* xp0 = reinterpret_cast<const f32x4*>(&sXH[0][kb << 3]);
                const f32x4* xp1 = reinterpret_cast<const f32x4*>(&sXH[1][kb << 3]);
                f32x4 xa0 = xp0[0], xb0 = xp0[1];
                f32x4 xa1 = xp1[0], xb1 = xp1[1];
                #pragma unroll
                for (int kk = 0; kk < 4; ++kk) {
                    float w0 = w2f((unsigned short)wvv[kk]);
                    float w1 = w2f((unsigned short)wvv[kk + 4]);
                    a0  += xa0[kk] * w0;  a1  += xa1[kk] * w0;
                    a0b += xb0[kk] * w1;  a1b += xb1[kk] * w1;
                }
            }
            #pragma unroll 4
            for (int kb = 0; kb < 16; ++kb) {
                short8 wvv = *reinterpret_cast<const short8*>(whp + ((kb << 9) + g) * 8);
                const f32x4* hp0 = reinterpret_cast<const f32x4*>(&sHin[0][kb << 3]);
                const f32x4* hp1 = reinterpret_cast<const f32x4*>(&sHin[1][kb << 3]);
                f32x4 ha0 = hp0[0], hb0 = hp0[1];
                f32x4 ha1 = hp1[0], hb1 = hp1[1];
                #pragma unroll
                for (int kk = 0; kk < 4; ++kk) {
                    float w0 = w2f((unsigned short)wvv[kk]);
                    float w1 = w2f((unsigned short)wvv[kk + 4]);
                    a0  += ha0[kk] * w0;  a1  += ha1[kk] * w0;
                    a0b += hb0[kk] * w1;  a1b += hb1[kk] * w1;
                }
            }
#endif
            sG[0][g] = a0 + a0b;
            sG[1][g] = a1 + a1b;
            __syncthreads();
            if (tid < 256) {
                int b = tid >> 7, u = tid & 127;
                float gi = sG[b][u], gf = sG[b][128 + u], gg = sG[b][256 + u], go = sG[b][384 + u];
                float c_ = sigm(gf) * sCs[l][b][u] + sigm(gi) * tanhf(gg);
                float h_ = sigm(go) * tanhf(c_);
                sCs[l][b][u] = c_;
                sHs[l][b][u] = h_;
                if (l == 2) sH2[b][u] = h_;
#if HAVE_DOT2
                float hn = __shfl_down(h_, 1, 64);
                if (!(u & 1)) sXp[b][u >> 1] = pack2f16(h_, hn);
#else
                sXH[b][u] = h_;                 // next layer's x
#endif
            } else if (l < 2) {
                int t2 = tid - 256;
#if HAVE_DOT2
                if (t2 < 128) {
                    int bb = t2 >> 6, uu = t2 & 63;
                    sHp[bb][uu] = pack2f16(sHs[l + 1][bb][2 * uu], sHs[l + 1][bb][2 * uu + 1]);
                }
#else
                int b = t2 >> 7, u = t2 & 127;
                sHin[b][u] = sHs[l + 1][b][u];
#endif
            }
            __syncthreads();
        }

        // ---- attention (256 threads per graph) ----
        for (int idx = wv; idx < len; idx += 4) {
            float f0, f1;
            if (idx < CF) {
                f0 = sF[group][idx * 128 + lane];
                f1 = sF[group][idx * 128 + 64 + lane];
            } else {
                long n = s0 + idx;
                f0 = feat[n * 128 + lane];
                f1 = feat[n * 128 + 64 + lane];
            }
            float p = f0 * sH2[group][lane] + f1 * sH2[group][64 + lane];
            for (int off = 32; off; off >>= 1) p += __shfl_down(p, off, 64);
            if (lane == 0) { if (idx < 512) sE[group][idx] = p; else esg[s0 + idx] = p; }
        }
        __syncthreads();
        auto ev = [&](int i) { return i < 512 ? sE[group][i] : esg[s0 + i]; };
        float lm = -1e30f;
        for (int i = t; i < len; i += 256) lm = fmaxf(lm, ev(i));
        for (int off = 32; off; off >>= 1) lm = fmaxf(lm, __shfl_down(lm, off, 64));
        if (lane == 0) sred[group][wv] = lm;
        __syncthreads();
        float mx = fmaxf(fmaxf(sred[group][0], sred[group][1]),
                         fmaxf(sred[group][2], sred[group][3]));
        __syncthreads();
        float ls = 0.f;
        for (int i = t; i < len; i += 256) {
            float e_ = expf(ev(i) - mx);
            if (i < 512) sE[group][i] = e_; else esg[s0 + i] = e_;
            ls += e_;
        }
        for (int off = 32; off; off >>= 1) ls += __shfl_down(ls, off, 64);
        if (lane == 0) sred[group][wv] = ls;
        __syncthreads();
        float inv = 1.f / (sred[group][0] + sred[group][1] + sred[group][2] + sred[group][3] + 1e-9f);
        // racc with 2 independent accumulators (load ILP); feat from LDS cache when possible
        float r0 = 0.f, r1 = 0.f;
        {
            int i = half;
            for (; i + 2 < len; i += 4) {
                float fa = (i < CF) ? sF[group][i * 128 + j]
                                    : feat[(long)(s0 + i) * 128 + j];
                float fb = (i + 2 < CF) ? sF[group][(i + 2) * 128 + j]
                                        : feat[(long)(s0 + i + 2) * 128 + j];
                r0 += ev(i) * fa;
                r1 += ev(i + 2) * fb;
            }
            for (; i < len; i += 2) {
                float fa = (i < CF) ? sF[group][i * 128 + j]
                                    : feat[(long)(s0 + i) * 128 + j];
                r0 += ev(i) * fa;
            }
        }
        sR[group][half][j] = r0 + r1;
        __syncthreads();
        float rr = (sR[group][0][j] + sR[group][1][j]) * inv;
        if (half == 0) {
            sQ[group][j] = sH2[group][j];        // q
            sQ[group][128 + j] = rr;             // r
        }

        if (t6 == 5) {
            __syncthreads();
            // ---- FFN head: comb(384) -> 300 -> 256 -> NTASK ----
            if (half == 0) {
                sE[group][j] = sH2[group][j];
                sE[group][128 + j] = rr;
            } else {
                sE[group][256 + j] = fpb[(long)(b0g + group) * 128 + j];
            }
            __syncthreads();
            const unsigned short* Wf1b = wb + O_WF1;
            const unsigned short* Wf2b = wb + O_WF2;
            const unsigned short* Wpb  = wb + O_WP;
            for (int task = tid; task < 600; task += 512) {
                int g = task / 300, u = task % 300;
                float acc = bf1[u];
                for (int k = 0; k < 384; ++k) acc += sE[g][k] * w2f(Wf1b[k * 300 + u]);
                s1b[g][u] = fmaxf(acc, 0.f);
            }
            __syncthreads();
            for (int task = tid; task < 512; task += 512) {
                int g = task >> 8, u = task & 255;
                float acc = bf2[u];
                for (int k = 0; k < 300; ++k) acc += s1b[g][k] * w2f(Wf2b[k * 256 + u]);
                s2[g][u] = fmaxf(acc, 0.f);
            }
            __syncthreads();
            for (int task = tid; task < 2 * NTASK; task += 512) {
                int g = task / NTASK, u = task % NTASK;
                float acc = bp[u];
                for (int k = 0; k < 256; ++k) acc += s2[g][k] * w2f(Wpb[k * NTASK + u]);
                out[(long)(b0g + g) * NTASK + u] = acc;
            }
        } else {
            __syncthreads();   // protect sQ/sE reuse before next iteration
        }
    }
}

extern "C" void kernel_launch(void* const* d_in, const int* in_sizes, int n_in,
                              void* d_out, int out_size, void* d_ws, size_t ws_size,
                              hipStream_t stream) {
    auto fp_ = [&](int i) { return (const float*)d_in[i]; };
    auto ip_ = [&](int i) { return (const int*)d_in[i]; };
    const float *nf = fp_(0), *ef = fp_(1), *fpv = fp_(2);
    const int *src = ip_(3), *dst = ip_(4), *gid = ip_(5);
    const float *Wn = fp_(6), *bn = fp_(7), *We1 = fp_(8), *be1 = fp_(9);
    const float *We2 = fp_(10), *be2 = fp_(11), *Wres = fp_(12);
    const float *Wgx = fp_(13), *bgx = fp_(14), *Wgh = fp_(15), *bgh = fp_(16);
    const float *Wep = fp_(17), *bep = fp_(18);
    const float *Wlx0 = fp_(19), *Wlh0 = fp_(20), *bl0 = fp_(21);
    const float *Wlx1 = fp_(22), *Wlh1 = fp_(23), *bl1 = fp_(24);
    const float *Wlx2 = fp_(25), *Wlh2 = fp_(26), *bl2 = fp_(27);
    const float *Wfp = fp_(28), *bfpv = fp_(29);
    const float *bng = fp_(30), *bnb = fp_(31), *bnm = fp_(32), *bnv = fp_(33);
    const float *Wf1 = fp_(34), *bf1 = fp_(35), *Wf2 = fp_(36), *bf2 = fp_(37);
    const float *Wp = fp_(38), *bp = fp_(39);

    char* w = (char*)d_ws;
    auto alloc = [&](size_t bytes) -> char* {
        char* p = w; w += (bytes + 255) & ~(size_t)255; return p;
    };
    float* hA = (float*)alloc((size_t)NN * 64 * 4);
    float* hB = (float*)alloc((size_t)NN * 64 * 4);
    unsigned short* hbA = (unsigned short*)alloc((size_t)NN * 64 * 2);
    unsigned short* hbB = (unsigned short*)alloc((size_t)NN * 64 * 2);
    unsigned short* we2thi = (unsigned short*)alloc((size_t)129 * 4096 * 2);
    unsigned short* wbf = (unsigned short*)alloc((size_t)NWB * 2);
    float* aggB = (float*)alloc((size_t)NN * 64 * 4);   // zeroed by kgruz
    char* zstart = w;                               // ---- zeroed region start ----
    float* aggA  = (float*)alloc((size_t)NN * 64 * 4);
    float* feat  = (float*)alloc((size_t)NN * 128 * 4);
    size_t zfloats = (size_t)(w - zstart) / 4;      // ---- zeroed region end ----
    float* es   = (float*)alloc((size_t)NN * 4);
    int*   seg  = (int*)alloc((size_t)(NB + 1) * 4);
    float* fpb  = (float*)alloc((size_t)NB * 128 * 4);
    float* xt   = (float*)alloc((size_t)128 * EPAD * 4);   // X_T edge-net activations

    // --- kpre section boundaries ---
    int nz4 = (int)(zfloats / 4);
    int zb  = (nz4 + 2047) / 2048;
    int B0 = zb;
    int B1 = B0 + 129;            // we2T: 1 block/chunk
    int B2 = B1 + 4;              // seg
    int B3 = B2 + NB;             // fpenc: 1 block/graph
    int B4 = B3 + 1250;           // nodeproj: 16 nodes/block
    int B5 = B4 + 235;            // xprep: 256 edges/block
    int B6 = B5 + (NWB + 2047) / 2048;  // weight conversion
    kpre<<<B6, 256, 0, stream>>>((float*)zstart, nz4, We2, be2, we2thi, gid, seg,
                                 fpv, Wfp, bfpv, bng, bnb, bnm, bnv, fpb,
                                 nf, Wn, bn, hA, hbA,
                                 ef, We1, be1, xt,
                                 Wlx0, Wlh0, Wlx1, Wlh1, Wlx2, Wlh2, Wf1, Wf2, Wp, wbf,
                                 B0, B1, B2, B3, B4, B5);

    float* hf[2] = {hA, hB};
    unsigned short* hb[2] = {hbA, hbB};
    float* aggbuf[2] = {aggA, aggB};
    int cur = 0;
    for (int it = 0; it < 3; ++it) {
        float* agg  = aggbuf[it & 1];
        float* aggN = aggbuf[1 - (it & 1)];
        keinsum<<<469 + 625, 256, 0, stream>>>(hb[cur], hf[cur], Wres,
                                               xt, we2thi, src, dst, agg);
        kgruz<<<625 + 157, 256, 0, stream>>>(agg, hf[cur], Wgx, bgx, Wgh, bgh,
                                             hf[1 - cur], hb[1 - cur], aggN);
        cur = 1 - cur;
    }
    kreadout<<<(NE * 128 + 255) / 256, 256, 0, stream>>>(hf[cur], ef, Wep, bep, src, dst, feat);

    klstmattn<<<NB / 2, 512, 0, stream>>>(feat, seg, es, wbf, bl0, bl1, bl2,
                                          fpb, bf1, bf2, bp, (float*)d_out);
}

// Round 14
// 805.041 us; speedup vs baseline: 1.3000x; 1.0250x over previous
//
#include <hip/hip_runtime.h>

typedef short short8 __attribute__((ext_vector_type(8)));
typedef float f32x4  __attribute__((ext_vector_type(4)));
typedef unsigned int u32x4 __attribute__((ext_vector_type(4)));
typedef _Float16 f16x2 __attribute__((ext_vector_type(2)));

#define NN 20000
#define NE 60000
#define NB 800
#define NTASK 138
#define EB 128     // edges per keinsum block
#define EPAD 60032 // padded edge count for X_T rows
#define CF 32      // cached feat rows per graph in klstmattn
#define CFS 132    // sF row stride (pad to break bank alignment)

// bf16 weight buffer offsets (shorts)
#define O_WX0 0
#define O_WH0 131072
#define O_WX1 196608
#define O_WH1 262144
#define O_WX2 327680
#define O_WH2 393216
#define O_WF1 458752
#define O_WF2 573952
#define O_WP  650752
#define NWB   686080

// v_dot2_f32_f16 availability (CDNA packed 2-way f16 dot w/ f32 accum)
#if defined(__has_builtin)
#if __has_builtin(__builtin_amdgcn_fdot2)
#define HAVE_DOT2 1
#else
#define HAVE_DOT2 0
#endif
#else
#define HAVE_DOT2 0
#endif

static __device__ __forceinline__ float sigm(float x) { return 1.f / (1.f + expf(-x)); }

static __device__ __forceinline__ unsigned short f2bf(float x) {
    unsigned u = __float_as_uint(x);
    unsigned r = (u + 0x7fffu + ((u >> 16) & 1u)) >> 16;
    return (unsigned short)r;
}
static __device__ __forceinline__ float bf2f(unsigned short b) {
    return __uint_as_float(((unsigned)b) << 16);
}

// LSTM/head weight encode-decode: f16 when dot2 available, else bf16
#if HAVE_DOT2
static __device__ __forceinline__ unsigned short f2w(float x) {
    _Float16 h = (_Float16)x;
    return __builtin_bit_cast(unsigned short, h);
}
static __device__ __forceinline__ float w2f(unsigned short s) {
    return (float)__builtin_bit_cast(_Float16, s);
}
static __device__ __forceinline__ unsigned int pack2f16(float a, float b) {
    unsigned short lo = __builtin_bit_cast(unsigned short, (_Float16)a);
    unsigned short hi = __builtin_bit_cast(unsigned short, (_Float16)b);
    return ((unsigned)hi << 16) | lo;
}
#define BC2(u) __builtin_bit_cast(f16x2, (unsigned int)(u))
#else
static __device__ __forceinline__ unsigned short f2w(float x) { return f2bf(x); }
static __device__ __forceinline__ float w2f(unsigned short s) { return bf2f(s); }
#endif

// =============== kpre: fused [zero | we2T | seg | fpenc | nodeproj | xprep | wcvt] ===============
__global__ void kpre(float* __restrict__ zbase, int nz4,
                     const float* __restrict__ We2, const float* __restrict__ be2,
                     unsigned short* __restrict__ thi,
                     const int* __restrict__ gid, int* __restrict__ seg,
                     const float* __restrict__ fpv, const float* __restrict__ Wfp,
                     const float* __restrict__ bfpv,
                     const float* __restrict__ bng, const float* __restrict__ bnb,
                     const float* __restrict__ bnm, const float* __restrict__ bnv,
                     float* __restrict__ fpb,
                     const float* __restrict__ nf, const float* __restrict__ Wn,
                     const float* __restrict__ bn, float* __restrict__ hf,
                     unsigned short* __restrict__ hb,
                     const float* __restrict__ ef, const float* __restrict__ We1,
                     const float* __restrict__ be1, float* __restrict__ xt,
                     const float* __restrict__ Wlx0, const float* __restrict__ Wlh0,
                     const float* __restrict__ Wlx1, const float* __restrict__ Wlh1,
                     const float* __restrict__ Wlx2, const float* __restrict__ Wlh2,
                     const float* __restrict__ Wf1, const float* __restrict__ Wf2,
                     const float* __restrict__ Wp, unsigned short* __restrict__ wb,
                     int B0, int B1, int B2, int B3, int B4, int B5) {
    __shared__ float st[64 * 65];       // we2 transpose tile
    __shared__ float sNF[16 * 134];     // nodeproj staging
    __shared__ float sred[128];
    __shared__ float sW[6 * 128];       // xprep We1 staging
    __shared__ float sbv[128];
    const int bid = blockIdx.x, tid = threadIdx.x;
    if (bid < B0) {
        long base = (long)bid * 2048 + tid;
        #pragma unroll
        for (int r = 0; r < 8; ++r) {
            long i = base + r * 256;
            if (i < nz4) reinterpret_cast<f32x4*>(zbase)[i] = f32x4{0.f, 0.f, 0.f, 0.f};
        }
    } else if (bid < B1) {
        int c = bid - B0;
        const float* srcp = (c < 128) ? We2 + (long)c * 4096 : be2;
        for (int idx = tid; idx < 4096; idx += 256) {
            int o = idx & 63, i = idx >> 6;
            st[o * 65 + i] = srcp[idx];
        }
        __syncthreads();
        for (int idx = tid; idx < 4096; idx += 256) {
            int i = idx & 63, o = idx >> 6;
            thi[(long)c * 4096 + idx] = f2bf(st[o * 65 + i]);
        }
    } else if (bid < B2) {
        int b = (bid - B1) * 256 + tid;
        if (b <= NB) {
            int lo = 0, hi = NN;
            while (lo < hi) { int mid = (lo + hi) >> 1; if (gid[mid] < b) lo = mid + 1; else hi = mid; }
            seg[b] = lo;
        }
    } else if (bid < B3) {
        int g = bid - B2;
        int u = tid & 127, half = tid >> 7;
        float acc = half ? 0.f : bfpv[u];
        const float* fr = fpv + (long)g * 1024 + half * 512;
        const float* wr = Wfp + (long)half * 512 * 128;
        for (int k = 0; k < 512; ++k) acc += fr[k] * wr[k * 128 + u];
        if (half) sred[u] = acc;
        __syncthreads();
        if (!half) {
            acc += sred[u];
            float sc = bng[u] / sqrtf(bnv[u] + 1e-5f);
            fpb[(long)g * 128 + u] = fmaxf((acc - bnm[u]) * sc + bnb[u], 0.f);
        }
    } else if (bid < B4) {
        int n0 = (bid - B3) * 16;
        const float* nfb = nf + (long)n0 * 134;
        for (int i = tid; i < 16 * 134; i += 256) sNF[i] = nfb[i];
        __syncthreads();
        int u = tid & 63, jg = tid >> 6;
        float a[4];
        float bv = bn[u];
        #pragma unroll
        for (int jj = 0; jj < 4; ++jj) a[jj] = bv;
        for (int k = 0; k < 134; ++k) {
            float w = Wn[k * 64 + u];
            #pragma unroll
            for (int jj = 0; jj < 4; ++jj) a[jj] += sNF[(jg * 4 + jj) * 134 + k] * w;
        }
        #pragma unroll
        for (int jj = 0; jj < 4; ++jj) {
            long o = (long)(n0 + jg * 4 + jj) * 64 + u;
            float v = fmaxf(a[jj], 0.f);
            hf[o] = v;
            hb[o] = f2bf(v);
        }
    } else if (bid < B5) {
        // xprep: X_T[c][e], column-major in e (coalesced stores)
        for (int i = tid; i < 768; i += 256) sW[i] = We1[i];
        if (tid < 128) sbv[tid] = be1[tid];
        __syncthreads();
        int e = (bid - B4) * 256 + tid;
        if (e < NE) {
            float e0 = ef[(long)e * 6 + 0], e1 = ef[(long)e * 6 + 1], e2 = ef[(long)e * 6 + 2];
            float e3 = ef[(long)e * 6 + 3], e4 = ef[(long)e * 6 + 4], e5 = ef[(long)e * 6 + 5];
            for (int c = 0; c < 128; ++c) {
                float a = sbv[c];
                a += e0 * sW[c];       a += e1 * sW[128 + c]; a += e2 * sW[256 + c];
                a += e3 * sW[384 + c]; a += e4 * sW[512 + c]; a += e5 * sW[640 + c];
                xt[(long)c * EPAD + e] = fmaxf(a, 0.f);
            }
        } else if (e < EPAD) {
            for (int c = 0; c < 128; ++c) xt[(long)c * EPAD + e] = 0.f;
        }
    } else {
        // weight conversion f32 -> f16/bf16; LSTM regions repacked to [K/8][512][8]
        int t0 = (bid - B5) * 2048 + tid;
        #pragma unroll
        for (int r = 0; r < 8; ++r) {
            int i = t0 + r * 256;
            if (i >= NWB) break;
            float v;
            if (i < O_WF1) {
                const float* srcp; int base;
                if (i < O_WH0)      { srcp = Wlx0; base = O_WX0; }
                else if (i < O_WX1) { srcp = Wlh0; base = O_WH0; }
                else if (i < O_WH1) { srcp = Wlx1; base = O_WX1; }
                else if (i < O_WX2) { srcp = Wlh1; base = O_WH1; }
                else if (i < O_WH2) { srcp = Wlx2; base = O_WX2; }
                else                { srcp = Wlh2; base = O_WH2; }
                int il = i - base;
                int kb = il >> 12, g = (il >> 3) & 511, kk = il & 7;
                v = srcp[(kb * 8 + kk) * 512 + g];
            }
            else if (i < O_WF2) v = Wf1[i - O_WF1];
            else if (i < O_WP)  v = Wf2[i - O_WF2];
            else                v = Wp[i - O_WP];
            wb[i] = f2w(v);
        }
    }
}

// =============== keinsum v12 (R7): 128 edges/block, GLOAD after barrier, X_T prefetch ===============
__global__ __launch_bounds__(256) void keinsum(
    const unsigned short* __restrict__ hb,
    const float* __restrict__ hf, const float* __restrict__ Wres,
    const float* __restrict__ xt,
    const unsigned short* __restrict__ thi,
    const int* __restrict__ src, const int* __restrict__ dst,
    float* __restrict__ agg) {
    __shared__ __align__(16) unsigned short sB[3 * 64 * 72];
    __shared__ __align__(16) float sX[3 * EB];
    const int bid = blockIdx.x, tid = threadIdx.x;
    if (bid >= 469) {
        int t = (bid - 469) * 256 + tid;
        int u = t & 63;
        int n0 = (t >> 6) * 8;
        if (n0 >= NN) return;
        float a[8] = {0.f, 0.f, 0.f, 0.f, 0.f, 0.f, 0.f, 0.f};
        for (int k = 0; k < 64; ++k) {
            float w = Wres[k * 64 + u];
            #pragma unroll
            for (int j = 0; j < 8; ++j) a[j] += hf[(long)(n0 + j) * 64 + k] * w;
        }
        #pragma unroll
        for (int j = 0; j < 8; ++j) atomicAdd(&agg[(long)(n0 + j) * 64 + u], a[j]);
        return;
    }
    const int lane = tid & 63, wave = tid >> 6;
    const int m = lane & 15, q = lane >> 4;
    const int eb = bid * EB;
    const int e0 = eb + wave * 32;

    short8 ahi[2][2];
    #pragma unroll
    for (int eg = 0; eg < 2; ++eg) {
        int em = e0 + eg * 16 + m; if (em >= NE) em = NE - 1;
        int sn = src[em];
        ahi[eg][0] = *reinterpret_cast<const short8*>(hb + (long)sn * 64 + q * 8);
        ahi[eg][1] = *reinterpret_cast<const short8*>(hb + (long)sn * 64 + 32 + q * 8);
    }
    float msg[2][4][4];
    #pragma unroll
    for (int eg = 0; eg < 2; ++eg)
        #pragma unroll
        for (int nt = 0; nt < 4; ++nt)
            #pragma unroll
            for (int r = 0; r < 4; ++r) msg[eg][nt][r] = 0.f;

    // named register sets (compile-time only -- rule #20)
    short8 rB0a, rB0b, rB1a, rB1b;
    float rX0, rX1;

    auto GLOAD0 = [&](int c) {
        const unsigned short* bb = thi + (long)c * 4096;
        rB0a = *reinterpret_cast<const short8*>(bb + tid * 8);
        rB0b = *reinterpret_cast<const short8*>(bb + (tid + 256) * 8);
        rX0 = (tid < EB) ? ((c < 128) ? xt[(long)c * EPAD + eb + tid] : 1.f) : 0.f;
    };
    auto GLOAD1 = [&](int c) {
        const unsigned short* bb = thi + (long)c * 4096;
        rB1a = *reinterpret_cast<const short8*>(bb + tid * 8);
        rB1b = *reinterpret_cast<const short8*>(bb + (tid + 256) * 8);
        rX1 = (tid < EB) ? ((c < 128) ? xt[(long)c * EPAD + eb + tid] : 1.f) : 0.f;
    };
    auto DSW0 = [&](int buf) {
        unsigned short* base = &sB[buf * 4608];
        *reinterpret_cast<short8*>(&base[(tid >> 3) * 72 + (tid & 7) * 8]) = rB0a;
        int u = tid + 256;
        *reinterpret_cast<short8*>(&base[(u >> 3) * 72 + (u & 7) * 8]) = rB0b;
        if (tid < EB) sX[buf * EB + tid] = rX0;
    };
    auto DSW1 = [&](int buf) {
        unsigned short* base = &sB[buf * 4608];
        *reinterpret_cast<short8*>(&base[(tid >> 3) * 72 + (tid & 7) * 8]) = rB1a;
        int u = tid + 256;
        *reinterpret_cast<short8*>(&base[(u >> 3) * 72 + (u & 7) * 8]) = rB1b;
        if (tid < EB) sX[buf * EB + tid] = rX1;
    };
    auto CMP = [&](int buf) {
        const unsigned short* base = &sB[buf * 4608];
        f32x4 xw[2];
        #pragma unroll
        for (int eg = 0; eg < 2; ++eg)
            xw[eg] = *reinterpret_cast<const f32x4*>(&sX[buf * EB + wave * 32 + eg * 16 + q * 4]);
        short8 b0[4], b1[4];
        #pragma unroll
        for (int nt = 0; nt < 4; ++nt) {
            const unsigned short* rp = &base[(nt * 16 + m) * 72 + q * 8];
            b0[nt] = *reinterpret_cast<const short8*>(rp);
            b1[nt] = *reinterpret_cast<const short8*>(rp + 32);
        }
        #pragma unroll
        for (int eg = 0; eg < 2; ++eg)
            #pragma unroll
            for (int nt = 0; nt < 4; ++nt) {
                f32x4 z = {0.f, 0.f, 0.f, 0.f};
                z = __builtin_amdgcn_mfma_f32_16x16x32_bf16(ahi[eg][0], b0[nt], z, 0, 0, 0);
                z = __builtin_amdgcn_mfma_f32_16x16x32_bf16(ahi[eg][1], b1[nt], z, 0, 0, 0);
                #pragma unroll
                for (int r = 0; r < 4; ++r) msg[eg][nt][r] += xw[eg][r] * z[r];
            }
    };

    // prologue
    GLOAD0(0);
    DSW0(0);
    GLOAD1(1);
    int c = 0;
    for (; c + 1 < 129; c += 2) {
        int s = c % 3;
        __syncthreads();
        if (c + 2 < 129) GLOAD0(c + 2);
        DSW1((s + 1) % 3);
        CMP(s);
        __syncthreads();
        if (c + 3 < 129) GLOAD1(c + 3);
        if (c + 2 < 129) DSW0((s + 2) % 3);
        CMP((s + 1) % 3);
    }
    if (c < 129) { __syncthreads(); CMP(c % 3); }

    #pragma unroll
    for (int eg = 0; eg < 2; ++eg)
        #pragma unroll
        for (int r = 0; r < 4; ++r) {
            int e = e0 + eg * 16 + q * 4 + r;
            if (e < NE) {
                int d = dst[e];
                #pragma unroll
                for (int nt = 0; nt < 4; ++nt)
                    atomicAdd(&agg[(long)d * 64 + nt * 16 + m], msg[eg][nt][r]);
            }
        }
}

// =============== kgruz: LDS-staged GRU (32 nodes/block) + zero next agg ===============
__global__ void kgruz(const float* __restrict__ agg, const float* __restrict__ h,
                      const float* __restrict__ Wgx, const float* __restrict__ bgx,
                      const float* __restrict__ Wgh, const float* __restrict__ bgh,
                      float* __restrict__ hof, unsigned short* __restrict__ hb,
                      float* __restrict__ aggN) {
    const int bid = blockIdx.x, tid = threadIdx.x;
    if (bid >= 625) {
        long base = (long)(bid - 625) * 2048 + tid;
        #pragma unroll
        for (int r = 0; r < 8; ++r) {
            long i = base + r * 256;
            if (i < 320000) reinterpret_cast<f32x4*>(aggN)[i] = f32x4{0.f, 0.f, 0.f, 0.f};
        }
        return;
    }
    __shared__ float sA[2048], sH[2048];
    const int n0 = bid * 32;
    const float* ab = agg + (long)n0 * 64;
    const float* hrow = h + (long)n0 * 64;
    for (int i = tid; i < 2048; i += 256) { sA[i] = ab[i]; sH[i] = hrow[i]; }
    __syncthreads();
    const int u = tid & 63, jg = tid >> 6;
    float xr[8], xz[8], xn[8], hr[8], hz[8], hn[8];
    float b0 = bgx[u], b1 = bgx[64 + u], b2 = bgx[128 + u];
    float d0 = bgh[u], d1 = bgh[64 + u], d2 = bgh[128 + u];
    #pragma unroll
    for (int j = 0; j < 8; ++j) {
        xr[j] = b0; xz[j] = b1; xn[j] = b2;
        hr[j] = d0; hz[j] = d1; hn[j] = d2;
    }
    for (int k = 0; k < 64; ++k) {
        float w0 = Wgx[k * 192 + u], w1 = Wgx[k * 192 + 64 + u], w2 = Wgx[k * 192 + 128 + u];
        float v0 = Wgh[k * 192 + u], v1 = Wgh[k * 192 + 64 + u], v2 = Wgh[k * 192 + 128 + u];
        #pragma unroll
        for (int j = 0; j < 8; ++j) {
            int n = jg * 8 + j;
            float mk = fmaxf(sA[n * 64 + k], 0.f);
            float hk = sH[n * 64 + k];
            xr[j] += mk * w0; xz[j] += mk * w1; xn[j] += mk * w2;
            hr[j] += hk * v0; hz[j] += hk * v1; hn[j] += hk * v2;
        }
    }
    #pragma unroll
    for (int j = 0; j < 8; ++j) {
        int n = jg * 8 + j;
        float rg = sigm(xr[j] + hr[j]);
        float zg = sigm(xz[j] + hz[j]);
        float ng = tanhf(xn[j] + rg * hn[j]);
        long o = (long)(n0 + n) * 64 + u;
        float hv = (1.f - zg) * ng + zg * sH[n * 64 + u];
        hof[o] = hv;
        hb[o] = f2bf(hv);
    }
}

// =============== readout scatter: feat[dst] += [h[src] | relu(ef@Wep+bep)] ===============
__global__ void kreadout(const float* __restrict__ h,
                         const float* __restrict__ ef, const float* __restrict__ Wep,
                         const float* __restrict__ bep,
                         const int* __restrict__ src, const int* __restrict__ dst,
                         float* __restrict__ feat) {
    int t = blockIdx.x * blockDim.x + threadIdx.x;
    if (t >= NE * 128) return;
    int e = t >> 7, j = t & 127;
    float v;
    if (j < 64) {
        v = h[(long)src[e] * 64 + j];
    } else {
        int o = j - 64;
        v = bep[o];
        #pragma unroll
        for (int k = 0; k < 6; ++k) v += ef[(long)e * 6 + k] * Wep[k * 64 + o];
        v = fmaxf(v, 0.f);
    }
    atomicAdd(&feat[(long)dst[e] * 128 + j], v);
}

// =============== klstmattn v9: v8 + 4-lane-per-row score pass (no 6-level shfl chain) ===============
// Score pass: each 4-lane group owns one row, lane sums 32 dims from padded sF (stride 132),
// 2 shfl_xor levels instead of 6 shfl_down. 16 rows in flight per wave (was 1).
// LSTM weight loops unroll 8 (deeper load pipeline; VGPR headroom ample, grid-limited occ).
__global__ __launch_bounds__(512) void klstmattn(
    const float* __restrict__ feat, const int* __restrict__ seg,
    float* __restrict__ esg,
    const unsigned short* __restrict__ wb,
    const float* __restrict__ bl0, const float* __restrict__ bl1, const float* __restrict__ bl2,
    const float* __restrict__ fpb,
    const float* __restrict__ bf1, const float* __restrict__ bf2, const float* __restrict__ bp,
    float* __restrict__ out) {
    __shared__ float sQ[2][256];    // q_star (persistent across iterations)
    __shared__ float sHs[3][2][128];// LSTM h state per layer
    __shared__ float sCs[3][2][128];// LSTM c state per layer
    __shared__ float sG[2][512];    // gates
    __shared__ float sE[2][512];    // attention scores/exp; reused as comb(384) in head
    __shared__ float sH2[2][128];   // layer-2 h (q)
    __shared__ float sR[2][2][128]; // racc partials
    __shared__ float sred[2][4];
    __shared__ float s1b[2][300];
    __shared__ float s2[2][256];
    __shared__ __align__(16) float sF[2][CF * CFS]; // cached feat rows (padded stride)
#if HAVE_DOT2
    __shared__ __align__(16) unsigned int sXp[2][128];  // packed f16 layer-input x
    __shared__ __align__(16) unsigned int sHp[2][64];   // packed f16 recurrent h_in
#else
    __shared__ float sXH[2][256];   // layer input x (f32 fallback)
    __shared__ float sHin[2][128];  // recurrent h_in (f32 fallback)
#endif
    const int tid = threadIdx.x;
    const int b0g = blockIdx.x * 2;
    const unsigned short* Wx[3] = {wb + O_WX0, wb + O_WX1, wb + O_WX2};
    const unsigned short* Wh[3] = {wb + O_WH0, wb + O_WH1, wb + O_WH2};
    const float* bl[3] = {bl0, bl1, bl2};

    const int group = tid >> 8;         // 0..1 (attention/head indexing)
    const int t = tid & 255;
    const int wv = t >> 6, lane = t & 63;
    const int j = t & 127, half = t >> 7;
    const int s0 = seg[b0g + group], s1 = seg[b0g + group + 1], len = s1 - s0;

    // zero-init persistent state + cache feat rows (one barrier covers all)
    sQ[tid >> 8][tid & 255] = 0.f;
    {
        float* hp = &sHs[0][0][0];
        float* cp = &sCs[0][0][0];
        for (int i = tid; i < 768; i += 512) { hp[i] = 0.f; cp[i] = 0.f; }
    }
    {
        int rows = len < CF ? len : CF;
        for (int i = t; i < rows * 128; i += 256)
            sF[group][(i >> 7) * CFS + (i & 127)] = feat[(long)(s0 + (i >> 7)) * 128 + (i & 127)];
    }
    __syncthreads();

    for (int t6 = 0; t6 < 6; ++t6) {
        // stage x (q_star) and layer-0 h_in
#if HAVE_DOT2
        if (tid < 256) {
            int b = tid >> 7, u = tid & 127;
            sXp[b][u] = pack2f16(sQ[b][2 * u], sQ[b][2 * u + 1]);
        } else if (tid < 384) {
            int t2 = tid - 256;
            int bb = t2 >> 6, uu = t2 & 63;
            sHp[bb][uu] = pack2f16(sHs[0][bb][2 * uu], sHs[0][bb][2 * uu + 1]);
        }
#else
        {
            int b = tid >> 8, u = tid & 255;
            sXH[b][u] = sQ[b][u];
            if (tid < 256) {
                int bb = tid >> 7, uu = tid & 127;
                sHin[bb][uu] = sHs[0][bb][uu];
            }
        }
#endif
        __syncthreads();

        // ---- 3-layer LSTM ----
        for (int l = 0; l < 3; ++l) {
            const int Kx = l ? 128 : 256;
            const int g = tid;
            const unsigned short* wxp = Wx[l];
            const unsigned short* whp = Wh[l];
            float bv = bl[l][g];
            float a0 = bv, a1 = bv, a0b = 0.f, a1b = 0.f;
#if HAVE_DOT2
            #pragma unroll 8
            for (int kb = 0; kb < (Kx >> 3); ++kb) {
                u32x4 wu = *reinterpret_cast<const u32x4*>(wxp + ((kb << 9) + g) * 8);
                u32x4 x0 = *reinterpret_cast<const u32x4*>(&sXp[0][kb << 2]);
                u32x4 x1 = *reinterpret_cast<const u32x4*>(&sXp[1][kb << 2]);
                a0  = __builtin_amdgcn_fdot2(BC2(wu[0]), BC2(x0[0]), a0,  false);
                a1  = __builtin_amdgcn_fdot2(BC2(wu[0]), BC2(x1[0]), a1,  false);
                a0b = __builtin_amdgcn_fdot2(BC2(wu[1]), BC2(x0[1]), a0b, false);
                a1b = __builtin_amdgcn_fdot2(BC2(wu[1]), BC2(x1[1]), a1b, false);
                a0  = __builtin_amdgcn_fdot2(BC2(wu[2]), BC2(x0[2]), a0,  false);
                a1  = __builtin_amdgcn_fdot2(BC2(wu[2]), BC2(x1[2]), a1,  false);
                a0b = __builtin_amdgcn_fdot2(BC2(wu[3]), BC2(x0[3]), a0b, false);
                a1b = __builtin_amdgcn_fdot2(BC2(wu[3]), BC2(x1[3]), a1b, false);
            }
            #pragma unroll 8
            for (int kb = 0; kb < 16; ++kb) {
                u32x4 wu = *reinterpret_cast<const u32x4*>(whp + ((kb << 9) + g) * 8);
                u32x4 h0 = *reinterpret_cast<const u32x4*>(&sHp[0][kb << 2]);
                u32x4 h1 = *reinterpret_cast<const u32x4*>(&sHp[1][kb << 2]);
                a0  = __builtin_amdgcn_fdot2(BC2(wu[0]), BC2(h0[0]), a0,  false);
                a1  = __builtin_amdgcn_fdot2(BC2(wu[0]), BC2(h1[0]), a1,  false);
                a0b = __builtin_amdgcn_fdot2(BC2(wu[1]), BC2(h0[1]), a0b, false);
                a1b = __builtin_amdgcn_fdot2(BC2(wu[1]), BC2(h1[1]), a1b, false);
                a0  = __builtin_amdgcn_fdot2(BC2(wu[2]), BC2(h0[2]), a0,  false);
                a1  = __builtin_amdgcn_fdot2(BC2(wu[2]), BC2(h1[2]), a1,  false);
                a0b = __builtin_amdgcn_fdot2(BC2(wu[3]), BC2(h0[3]), a0b, false);
                a1b = __builtin_amdgcn_fdot2(BC2(wu[3]), BC2(h1[3]), a1b, false);
            }
#else
            #pragma unroll 8
            for (int kb = 0; kb < (Kx >> 3); ++kb) {
                short8 wvv = *reinterpret_cast<const short8*>(wxp + ((kb << 9) + g) * 8);
                const f32x4* xp0 = reinterpret_cast<const f32x4*>(&sXH[0][kb << 3]);
                const f32x4* xp1 = reinterpret_cast<const f32x4*>(&sXH[1][kb << 3]);
                f32x4 xa0 = xp0[0], xb0 = xp0[1];
                f32x4 xa1 = xp1[0], xb1 = xp1[1];
                #pragma unroll
                for (int kk = 0; kk < 4; ++kk) {
                    float w0 = w2f((unsigned short)wvv[kk]);
                    float w1 = w2f((unsigned short)wvv[kk + 4]);
                    a0  += xa0[kk] * w0;  a1  += xa1[kk] * w0;
                    a0b += xb0[kk] * w1;  a1b += xb1[kk] * w1;
                }
            }
            #pragma unroll 8
            for (int kb = 0; kb < 16; ++kb) {
                short8 wvv = *reinterpret_cast<const short8*>(whp + ((kb << 9) + g) * 8);
                const f32x4* hp0 = reinterpret_cast<const f32x4*>(&sHin[0][kb << 3]);
                const f32x4* hp1 = reinterpret_cast<const f32x4*>(&sHin[1][kb << 3]);
                f32x4 ha0 = hp0[0], hb0 = hp0[1];
                f32x4 ha1 = hp0[1], hb1 = hp1[1];
                #pragma unroll
                for (int kk = 0; kk < 4; ++kk) {
                    float w0 = w2f((unsigned short)wvv[kk]);
                    float w1 = w2f((unsigned short)wvv[kk + 4]);
                    a0  += ha0[kk] * w0;  a1  += ha1[kk] * w0;
                    a0b += hb0[kk] * w1;  a1b += hb1[kk] * w1;
                }
            }
#endif
            sG[0][g] = a0 + a0b;
            sG[1][g] = a1 + a1b;
            __syncthreads();
            if (tid < 256) {
                int b = tid >> 7, u = tid & 127;
                float gi = sG[b][u], gf = sG[b][128 + u], gg = sG[b][256 + u], go = sG[b][384 + u];
                float c_ = sigm(gf) * sCs[l][b][u] + sigm(gi) * tanhf(gg);
                float h_ = sigm(go) * tanhf(c_);
                sCs[l][b][u] = c_;
                sHs[l][b][u] = h_;
                if (l == 2) sH2[b][u] = h_;
#if HAVE_DOT2
                float hn = __shfl_down(h_, 1, 64);
                if (!(u & 1)) sXp[b][u >> 1] = pack2f16(h_, hn);
#else
                sXH[b][u] = h_;                 // next layer's x
#endif
            } else if (l < 2) {
                int t2 = tid - 256;
#if HAVE_DOT2
                if (t2 < 128) {
                    int bb = t2 >> 6, uu = t2 & 63;
                    sHp[bb][uu] = pack2f16(sHs[l + 1][bb][2 * uu], sHs[l + 1][bb][2 * uu + 1]);
                }
#else
                int b = t2 >> 7, u = t2 & 127;
                sHin[b][u] = sHs[l + 1][b][u];
#endif
            }
            __syncthreads();
        }

        // ---- attention (256 threads per graph) ----
        // score: 4 lanes per row, lane sums 32 dims, 2-level shfl_xor combine
        for (int base = wv * 16; base < len; base += 64) {
            int r = base + (lane >> 2);
            float p = 0.f;
            if (r < len) {
                const int d0 = (lane & 3) * 32;
                const float* qp = &sH2[group][d0];
                if (r < CF) {
                    const float* fp = &sF[group][r * CFS + d0];
                    #pragma unroll
                    for (int k = 0; k < 32; k += 4) {
                        f32x4 fv = *reinterpret_cast<const f32x4*>(fp + k);
                        p += fv[0] * qp[k] + fv[1] * qp[k + 1]
                           + fv[2] * qp[k + 2] + fv[3] * qp[k + 3];
                    }
                } else {
                    const float* fp = &feat[(long)(s0 + r) * 128 + d0];
                    #pragma unroll
                    for (int k = 0; k < 32; k += 4) {
                        f32x4 fv = *reinterpret_cast<const f32x4*>(fp + k);
                        p += fv[0] * qp[k] + fv[1] * qp[k + 1]
                           + fv[2] * qp[k + 2] + fv[3] * qp[k + 3];
                    }
                }
            }
            p += __shfl_xor(p, 1, 64);
            p += __shfl_xor(p, 2, 64);
            if ((lane & 3) == 0 && r < len) {
                if (r < 512) sE[group][r] = p; else esg[s0 + r] = p;
            }
        }
        __syncthreads();
        auto ev = [&](int i) { return i < 512 ? sE[group][i] : esg[s0 + i]; };
        float lm = -1e30f;
        for (int i = t; i < len; i += 256) lm = fmaxf(lm, ev(i));
        for (int off = 32; off; off >>= 1) lm = fmaxf(lm, __shfl_down(lm, off, 64));
        if (lane == 0) sred[group][wv] = lm;
        __syncthreads();
        float mx = fmaxf(fmaxf(sred[group][0], sred[group][1]),
                         fmaxf(sred[group][2], sred[group][3]));
        __syncthreads();
        float ls = 0.f;
        for (int i = t; i < len; i += 256) {
            float e_ = expf(ev(i) - mx);
            if (i < 512) sE[group][i] = e_; else esg[s0 + i] = e_;
            ls += e_;
        }
        for (int off = 32; off; off >>= 1) ls += __shfl_down(ls, off, 64);
        if (lane == 0) sred[group][wv] = ls;
        __syncthreads();
        float inv = 1.f / (sred[group][0] + sred[group][1] + sred[group][2] + sred[group][3] + 1e-9f);
        // racc with 2 independent accumulators (load ILP); feat from LDS cache when possible
        float r0 = 0.f, r1 = 0.f;
        {
            int i = half;
            for (; i + 2 < len; i += 4) {
                float fa = (i < CF) ? sF[group][i * CFS + j]
                                    : feat[(long)(s0 + i) * 128 + j];
                float fb = (i + 2 < CF) ? sF[group][(i + 2) * CFS + j]
                                        : feat[(long)(s0 + i + 2) * 128 + j];
                r0 += ev(i) * fa;
                r1 += ev(i + 2) * fb;
            }
            for (; i < len; i += 2) {
                float fa = (i < CF) ? sF[group][i * CFS + j]
                                    : feat[(long)(s0 + i) * 128 + j];
                r0 += ev(i) * fa;
            }
        }
        sR[group][half][j] = r0 + r1;
        __syncthreads();
        float rr = (sR[group][0][j] + sR[group][1][j]) * inv;
        if (half == 0) {
            sQ[group][j] = sH2[group][j];        // q
            sQ[group][128 + j] = rr;             // r
        }

        if (t6 == 5) {
            __syncthreads();
            // ---- FFN head: comb(384) -> 300 -> 256 -> NTASK ----
            if (half == 0) {
                sE[group][j] = sH2[group][j];
                sE[group][128 + j] = rr;
            } else {
                sE[group][256 + j] = fpb[(long)(b0g + group) * 128 + j];
            }
            __syncthreads();
            const unsigned short* Wf1b = wb + O_WF1;
            const unsigned short* Wf2b = wb + O_WF2;
            const unsigned short* Wpb  = wb + O_WP;
            for (int task = tid; task < 600; task += 512) {
                int g = task / 300, u = task % 300;
                float acc = bf1[u];
                for (int k = 0; k < 384; ++k) acc += sE[g][k] * w2f(Wf1b[k * 300 + u]);
                s1b[g][u] = fmaxf(acc, 0.f);
            }
            __syncthreads();
            for (int task = tid; task < 512; task += 512) {
                int g = task >> 8, u = task & 255;
                float acc = bf2[u];
                for (int k = 0; k < 300; ++k) acc += s1b[g][k] * w2f(Wf2b[k * 256 + u]);
                s2[g][u] = fmaxf(acc, 0.f);
            }
            __syncthreads();
            for (int task = tid; task < 2 * NTASK; task += 512) {
                int g = task / NTASK, u = task % NTASK;
                float acc = bp[u];
                for (int k = 0; k < 256; ++k) acc += s2[g][k] * w2f(Wpb[k * NTASK + u]);
                out[(long)(b0g + g) * NTASK + u] = acc;
            }
        } else {
            __syncthreads();   // protect sQ/sE reuse before next iteration
        }
    }
}

extern "C" void kernel_launch(void* const* d_in, const int* in_sizes, int n_in,
                              void* d_out, int out_size, void* d_ws, size_t ws_size,
                              hipStream_t stream) {
    auto fp_ = [&](int i) { return (const float*)d_in[i]; };
    auto ip_ = [&](int i) { return (const int*)d_in[i]; };
    const float *nf = fp_(0), *ef = fp_(1), *fpv = fp_(2);
    const int *src = ip_(3), *dst = ip_(4), *gid = ip_(5);
    const float *Wn = fp_(6), *bn = fp_(7), *We1 = fp_(8), *be1 = fp_(9);
    const float *We2 = fp_(10), *be2 = fp_(11), *Wres = fp_(12);
    const float *Wgx = fp_(13), *bgx = fp_(14), *Wgh = fp_(15), *bgh = fp_(16);
    const float *Wep = fp_(17), *bep = fp_(18);
    const float *Wlx0 = fp_(19), *Wlh0 = fp_(20), *bl0 = fp_(21);
    const float *Wlx1 = fp_(22), *Wlh1 = fp_(23), *bl1 = fp_(24);
    const float *Wlx2 = fp_(25), *Wlh2 = fp_(26), *bl2 = fp_(27);
    const float *Wfp = fp_(28), *bfpv = fp_(29);
    const float *bng = fp_(30), *bnb = fp_(31), *bnm = fp_(32), *bnv = fp_(33);
    const float *Wf1 = fp_(34), *bf1 = fp_(35), *Wf2 = fp_(36), *bf2 = fp_(37);
    const float *Wp = fp_(38), *bp = fp_(39);

    char* w = (char*)d_ws;
    auto alloc = [&](size_t bytes) -> char* {
        char* p = w; w += (bytes + 255) & ~(size_t)255; return p;
    };
    float* hA = (float*)alloc((size_t)NN * 64 * 4);
    float* hB = (float*)alloc((size_t)NN * 64 * 4);
    unsigned short* hbA = (unsigned short*)alloc((size_t)NN * 64 * 2);
    unsigned short* hbB = (unsigned short*)alloc((size_t)NN * 64 * 2);
    unsigned short* we2thi = (unsigned short*)alloc((size_t)129 * 4096 * 2);
    unsigned short* wbf = (unsigned short*)alloc((size_t)NWB * 2);
    float* aggB = (float*)alloc((size_t)NN * 64 * 4);   // zeroed by kgruz
    char* zstart = w;                               // ---- zeroed region start ----
    float* aggA  = (float*)alloc((size_t)NN * 64 * 4);
    float* feat  = (float*)alloc((size_t)NN * 128 * 4);
    size_t zfloats = (size_t)(w - zstart) / 4;      // ---- zeroed region end ----
    float* es   = (float*)alloc((size_t)NN * 4);
    int*   seg  = (int*)alloc((size_t)(NB + 1) * 4);
    float* fpb  = (float*)alloc((size_t)NB * 128 * 4);
    float* xt   = (float*)alloc((size_t)128 * EPAD * 4);   // X_T edge-net activations

    // --- kpre section boundaries ---
    int nz4 = (int)(zfloats / 4);
    int zb  = (nz4 + 2047) / 2048;
    int B0 = zb;
    int B1 = B0 + 129;            // we2T: 1 block/chunk
    int B2 = B1 + 4;              // seg
    int B3 = B2 + NB;             // fpenc: 1 block/graph
    int B4 = B3 + 1250;           // nodeproj: 16 nodes/block
    int B5 = B4 + 235;            // xprep: 256 edges/block
    int B6 = B5 + (NWB + 2047) / 2048;  // weight conversion
    kpre<<<B6, 256, 0, stream>>>((float*)zstart, nz4, We2, be2, we2thi, gid, seg,
                                 fpv, Wfp, bfpv, bng, bnb, bnm, bnv, fpb,
                                 nf, Wn, bn, hA, hbA,
                                 ef, We1, be1, xt,
                                 Wlx0, Wlh0, Wlx1, Wlh1, Wlx2, Wlh2, Wf1, Wf2, Wp, wbf,
                                 B0, B1, B2, B3, B4, B5);

    float* hf[2] = {hA, hB};
    unsigned short* hb[2] = {hbA, hbB};
    float* aggbuf[2] = {aggA, aggB};
    int cur = 0;
    for (int it = 0; it < 3; ++it) {
        float* agg  = aggbuf[it & 1];
        float* aggN = aggbuf[1 - (it & 1)];
        keinsum<<<469 + 625, 256, 0, stream>>>(hb[cur], hf[cur], Wres,
                                               xt, we2thi, src, dst, agg);
        kgruz<<<625 + 157, 256, 0, stream>>>(agg, hf[cur], Wgx, bgx, Wgh, bgh,
                                             hf[1 - cur], hb[1 - cur], aggN);
        cur = 1 - cur;
    }
    kreadout<<<(NE * 128 + 255) / 256, 256, 0, stream>>>(hf[cur], ef, Wep, bep, src, dst, feat);

    klstmattn<<<NB / 2, 512, 0, stream>>>(feat, seg, es, wbf, bl0, bl1, bl2,
                                          fpb, bf1, bf2, bp, (float*)d_out);
}

// Round 15
// 790.318 us; speedup vs baseline: 1.3242x; 1.0186x over previous
//
#include <hip/hip_runtime.h>

typedef short short8 __attribute__((ext_vector_type(8)));
typedef float f32x4  __attribute__((ext_vector_type(4)));
typedef unsigned int u32x4 __attribute__((ext_vector_type(4)));
typedef _Float16 f16x2 __attribute__((ext_vector_type(2)));

#define NN 20000
#define NE 60000
#define NB 800
#define NTASK 138
#define EB 128     // edges per keinsum block
#define EPAD 60032 // padded edge count for X_T rows
#define CF 32      // cached feat rows per graph in klstmattn
#define CFS 132    // sF row stride

// bf16 weight buffer offsets (shorts)
#define O_WX0 0
#define O_WH0 131072
#define O_WX1 196608
#define O_WH1 262144
#define O_WX2 327680
#define O_WH2 393216
#define O_WF1 458752
#define O_WF2 573952
#define O_WP  650752
#define NWB   686080

// v_dot2_f32_f16 availability (CDNA packed 2-way f16 dot w/ f32 accum)
#if defined(__has_builtin)
#if __has_builtin(__builtin_amdgcn_fdot2)
#define HAVE_DOT2 1
#else
#define HAVE_DOT2 0
#endif
#else
#define HAVE_DOT2 0
#endif

static __device__ __forceinline__ float sigm(float x) { return 1.f / (1.f + expf(-x)); }

static __device__ __forceinline__ unsigned short f2bf(float x) {
    unsigned u = __float_as_uint(x);
    unsigned r = (u + 0x7fffu + ((u >> 16) & 1u)) >> 16;
    return (unsigned short)r;
}
static __device__ __forceinline__ float bf2f(unsigned short b) {
    return __uint_as_float(((unsigned)b) << 16);
}

// LSTM/head weight encode-decode: f16 when dot2 available, else bf16
#if HAVE_DOT2
static __device__ __forceinline__ unsigned short f2w(float x) {
    _Float16 h = (_Float16)x;
    return __builtin_bit_cast(unsigned short, h);
}
static __device__ __forceinline__ float w2f(unsigned short s) {
    return (float)__builtin_bit_cast(_Float16, s);
}
static __device__ __forceinline__ unsigned int pack2f16(float a, float b) {
    unsigned short lo = __builtin_bit_cast(unsigned short, (_Float16)a);
    unsigned short hi = __builtin_bit_cast(unsigned short, (_Float16)b);
    return ((unsigned)hi << 16) | lo;
}
#define BC2(u) __builtin_bit_cast(f16x2, (unsigned int)(u))
#else
static __device__ __forceinline__ unsigned short f2w(float x) { return f2bf(x); }
static __device__ __forceinline__ float w2f(unsigned short s) { return bf2f(s); }
#endif

// =============== kpre: fused [zero | we2T | seg | fpenc | nodeproj | xprep | gruT | wcvt] ===============
// gruT: GRU weights repacked to [k/4][192][4] f32 (coalesced f32x4 loads in kgruz)
__global__ void kpre(float* __restrict__ zbase, int nz4,
                     const float* __restrict__ We2, const float* __restrict__ be2,
                     unsigned short* __restrict__ thi,
                     const int* __restrict__ gid, int* __restrict__ seg,
                     const float* __restrict__ fpv, const float* __restrict__ Wfp,
                     const float* __restrict__ bfpv,
                     const float* __restrict__ bng, const float* __restrict__ bnb,
                     const float* __restrict__ bnm, const float* __restrict__ bnv,
                     float* __restrict__ fpb,
                     const float* __restrict__ nf, const float* __restrict__ Wn,
                     const float* __restrict__ bn, float* __restrict__ hf,
                     unsigned short* __restrict__ hb,
                     const float* __restrict__ ef, const float* __restrict__ We1,
                     const float* __restrict__ be1, float* __restrict__ xt,
                     const float* __restrict__ Wgx, const float* __restrict__ Wgh,
                     float* __restrict__ wgxt, float* __restrict__ wght,
                     const float* __restrict__ Wlx0, const float* __restrict__ Wlh0,
                     const float* __restrict__ Wlx1, const float* __restrict__ Wlh1,
                     const float* __restrict__ Wlx2, const float* __restrict__ Wlh2,
                     const float* __restrict__ Wf1, const float* __restrict__ Wf2,
                     const float* __restrict__ Wp, unsigned short* __restrict__ wb,
                     int B0, int B1, int B2, int B3, int B4, int B5, int B6) {
    __shared__ float st[64 * 65];       // we2 transpose tile
    __shared__ float sNF[16 * 134];     // nodeproj staging
    __shared__ float sred[128];
    __shared__ float sW[6 * 128];       // xprep We1 staging
    __shared__ float sbv[128];
    const int bid = blockIdx.x, tid = threadIdx.x;
    if (bid < B0) {
        long base = (long)bid * 2048 + tid;
        #pragma unroll
        for (int r = 0; r < 8; ++r) {
            long i = base + r * 256;
            if (i < nz4) reinterpret_cast<f32x4*>(zbase)[i] = f32x4{0.f, 0.f, 0.f, 0.f};
        }
    } else if (bid < B1) {
        int c = bid - B0;
        const float* srcp = (c < 128) ? We2 + (long)c * 4096 : be2;
        for (int idx = tid; idx < 4096; idx += 256) {
            int o = idx & 63, i = idx >> 6;
            st[o * 65 + i] = srcp[idx];
        }
        __syncthreads();
        for (int idx = tid; idx < 4096; idx += 256) {
            int i = idx & 63, o = idx >> 6;
            thi[(long)c * 4096 + idx] = f2bf(st[o * 65 + i]);
        }
    } else if (bid < B2) {
        int b = (bid - B1) * 256 + tid;
        if (b <= NB) {
            int lo = 0, hi = NN;
            while (lo < hi) { int mid = (lo + hi) >> 1; if (gid[mid] < b) lo = mid + 1; else hi = mid; }
            seg[b] = lo;
        }
    } else if (bid < B3) {
        int g = bid - B2;
        int u = tid & 127, half = tid >> 7;
        float acc = half ? 0.f : bfpv[u];
        const float* fr = fpv + (long)g * 1024 + half * 512;
        const float* wr = Wfp + (long)half * 512 * 128;
        for (int k = 0; k < 512; ++k) acc += fr[k] * wr[k * 128 + u];
        if (half) sred[u] = acc;
        __syncthreads();
        if (!half) {
            acc += sred[u];
            float sc = bng[u] / sqrtf(bnv[u] + 1e-5f);
            fpb[(long)g * 128 + u] = fmaxf((acc - bnm[u]) * sc + bnb[u], 0.f);
        }
    } else if (bid < B4) {
        int n0 = (bid - B3) * 16;
        const float* nfb = nf + (long)n0 * 134;
        for (int i = tid; i < 16 * 134; i += 256) sNF[i] = nfb[i];
        __syncthreads();
        int u = tid & 63, jg = tid >> 6;
        float a[4];
        float bv = bn[u];
        #pragma unroll
        for (int jj = 0; jj < 4; ++jj) a[jj] = bv;
        for (int k = 0; k < 134; ++k) {
            float w = Wn[k * 64 + u];
            #pragma unroll
            for (int jj = 0; jj < 4; ++jj) a[jj] += sNF[(jg * 4 + jj) * 134 + k] * w;
        }
        #pragma unroll
        for (int jj = 0; jj < 4; ++jj) {
            long o = (long)(n0 + jg * 4 + jj) * 64 + u;
            float v = fmaxf(a[jj], 0.f);
            hf[o] = v;
            hb[o] = f2bf(v);
        }
    } else if (bid < B5) {
        // xprep: X_T[c][e], column-major in e (coalesced stores)
        for (int i = tid; i < 768; i += 256) sW[i] = We1[i];
        if (tid < 128) sbv[tid] = be1[tid];
        __syncthreads();
        int e = (bid - B4) * 256 + tid;
        if (e < NE) {
            float e0 = ef[(long)e * 6 + 0], e1 = ef[(long)e * 6 + 1], e2 = ef[(long)e * 6 + 2];
            float e3 = ef[(long)e * 6 + 3], e4 = ef[(long)e * 6 + 4], e5 = ef[(long)e * 6 + 5];
            for (int c = 0; c < 128; ++c) {
                float a = sbv[c];
                a += e0 * sW[c];       a += e1 * sW[128 + c]; a += e2 * sW[256 + c];
                a += e3 * sW[384 + c]; a += e4 * sW[512 + c]; a += e5 * sW[640 + c];
                xt[(long)c * EPAD + e] = fmaxf(a, 0.f);
            }
        } else if (e < EPAD) {
            for (int c = 0; c < 128; ++c) xt[(long)c * EPAD + e] = 0.f;
        }
    } else if (bid < B6) {
        // gruT: repack Wg{x,h}[k][192] -> wt[(k>>2)*192*4 + u3*4 + (k&3)]
        int mt = bid - B5;          // 0: Wgx, 1: Wgh
        const float* s = mt ? Wgh : Wgx;
        float* d = mt ? wght : wgxt;
        for (int i = tid; i < 192 * 64; i += 256) {
            int u3 = i >> 6, k = i & 63;
            d[(k >> 2) * 768 + u3 * 4 + (k & 3)] = s[k * 192 + u3];
        }
    } else {
        // weight conversion f32 -> f16/bf16; LSTM regions repacked to [K/8][512][8]
        int t0 = (bid - B6) * 2048 + tid;
        #pragma unroll
        for (int r = 0; r < 8; ++r) {
            int i = t0 + r * 256;
            if (i >= NWB) break;
            float v;
            if (i < O_WF1) {
                const float* srcp; int base;
                if (i < O_WH0)      { srcp = Wlx0; base = O_WX0; }
                else if (i < O_WX1) { srcp = Wlh0; base = O_WH0; }
                else if (i < O_WH1) { srcp = Wlx1; base = O_WX1; }
                else if (i < O_WX2) { srcp = Wlh1; base = O_WH1; }
                else if (i < O_WH2) { srcp = Wlx2; base = O_WX2; }
                else                { srcp = Wlh2; base = O_WH2; }
                int il = i - base;
                int kb = il >> 12, g = (il >> 3) & 511, kk = il & 7;
                v = srcp[(kb * 8 + kk) * 512 + g];
            }
            else if (i < O_WF2) v = Wf1[i - O_WF1];
            else if (i < O_WP)  v = Wf2[i - O_WF2];
            else                v = Wp[i - O_WP];
            wb[i] = f2w(v);
        }
    }
}

// =============== keinsum v12 (R7): 128 edges/block, GLOAD after barrier, X_T prefetch ===============
__global__ __launch_bounds__(256) void keinsum(
    const unsigned short* __restrict__ hb,
    const float* __restrict__ hf, const float* __restrict__ Wres,
    const float* __restrict__ xt,
    const unsigned short* __restrict__ thi,
    const int* __restrict__ src, const int* __restrict__ dst,
    float* __restrict__ agg) {
    __shared__ __align__(16) unsigned short sB[3 * 64 * 72];
    __shared__ __align__(16) float sX[3 * EB];
    const int bid = blockIdx.x, tid = threadIdx.x;
    if (bid >= 469) {
        int t = (bid - 469) * 256 + tid;
        int u = t & 63;
        int n0 = (t >> 6) * 8;
        if (n0 >= NN) return;
        float a[8] = {0.f, 0.f, 0.f, 0.f, 0.f, 0.f, 0.f, 0.f};
        for (int k = 0; k < 64; ++k) {
            float w = Wres[k * 64 + u];
            #pragma unroll
            for (int j = 0; j < 8; ++j) a[j] += hf[(long)(n0 + j) * 64 + k] * w;
        }
        #pragma unroll
        for (int j = 0; j < 8; ++j) atomicAdd(&agg[(long)(n0 + j) * 64 + u], a[j]);
        return;
    }
    const int lane = tid & 63, wave = tid >> 6;
    const int m = lane & 15, q = lane >> 4;
    const int eb = bid * EB;
    const int e0 = eb + wave * 32;

    short8 ahi[2][2];
    #pragma unroll
    for (int eg = 0; eg < 2; ++eg) {
        int em = e0 + eg * 16 + m; if (em >= NE) em = NE - 1;
        int sn = src[em];
        ahi[eg][0] = *reinterpret_cast<const short8*>(hb + (long)sn * 64 + q * 8);
        ahi[eg][1] = *reinterpret_cast<const short8*>(hb + (long)sn * 64 + 32 + q * 8);
    }
    float msg[2][4][4];
    #pragma unroll
    for (int eg = 0; eg < 2; ++eg)
        #pragma unroll
        for (int nt = 0; nt < 4; ++nt)
            #pragma unroll
            for (int r = 0; r < 4; ++r) msg[eg][nt][r] = 0.f;

    // named register sets (compile-time only -- rule #20)
    short8 rB0a, rB0b, rB1a, rB1b;
    float rX0, rX1;

    auto GLOAD0 = [&](int c) {
        const unsigned short* bb = thi + (long)c * 4096;
        rB0a = *reinterpret_cast<const short8*>(bb + tid * 8);
        rB0b = *reinterpret_cast<const short8*>(bb + (tid + 256) * 8);
        rX0 = (tid < EB) ? ((c < 128) ? xt[(long)c * EPAD + eb + tid] : 1.f) : 0.f;
    };
    auto GLOAD1 = [&](int c) {
        const unsigned short* bb = thi + (long)c * 4096;
        rB1a = *reinterpret_cast<const short8*>(bb + tid * 8);
        rB1b = *reinterpret_cast<const short8*>(bb + (tid + 256) * 8);
        rX1 = (tid < EB) ? ((c < 128) ? xt[(long)c * EPAD + eb + tid] : 1.f) : 0.f;
    };
    auto DSW0 = [&](int buf) {
        unsigned short* base = &sB[buf * 4608];
        *reinterpret_cast<short8*>(&base[(tid >> 3) * 72 + (tid & 7) * 8]) = rB0a;
        int u = tid + 256;
        *reinterpret_cast<short8*>(&base[(u >> 3) * 72 + (u & 7) * 8]) = rB0b;
        if (tid < EB) sX[buf * EB + tid] = rX0;
    };
    auto DSW1 = [&](int buf) {
        unsigned short* base = &sB[buf * 4608];
        *reinterpret_cast<short8*>(&base[(tid >> 3) * 72 + (tid & 7) * 8]) = rB1a;
        int u = tid + 256;
        *reinterpret_cast<short8*>(&base[(u >> 3) * 72 + (u & 7) * 8]) = rB1b;
        if (tid < EB) sX[buf * EB + tid] = rX1;
    };
    auto CMP = [&](int buf) {
        const unsigned short* base = &sB[buf * 4608];
        f32x4 xw[2];
        #pragma unroll
        for (int eg = 0; eg < 2; ++eg)
            xw[eg] = *reinterpret_cast<const f32x4*>(&sX[buf * EB + wave * 32 + eg * 16 + q * 4]);
        short8 b0[4], b1[4];
        #pragma unroll
        for (int nt = 0; nt < 4; ++nt) {
            const unsigned short* rp = &base[(nt * 16 + m) * 72 + q * 8];
            b0[nt] = *reinterpret_cast<const short8*>(rp);
            b1[nt] = *reinterpret_cast<const short8*>(rp + 32);
        }
        #pragma unroll
        for (int eg = 0; eg < 2; ++eg)
            #pragma unroll
            for (int nt = 0; nt < 4; ++nt) {
                f32x4 z = {0.f, 0.f, 0.f, 0.f};
                z = __builtin_amdgcn_mfma_f32_16x16x32_bf16(ahi[eg][0], b0[nt], z, 0, 0, 0);
                z = __builtin_amdgcn_mfma_f32_16x16x32_bf16(ahi[eg][1], b1[nt], z, 0, 0, 0);
                #pragma unroll
                for (int r = 0; r < 4; ++r) msg[eg][nt][r] += xw[eg][r] * z[r];
            }
    };

    // prologue
    GLOAD0(0);
    DSW0(0);
    GLOAD1(1);
    int c = 0;
    for (; c + 1 < 129; c += 2) {
        int s = c % 3;
        __syncthreads();
        if (c + 2 < 129) GLOAD0(c + 2);
        DSW1((s + 1) % 3);
        CMP(s);
        __syncthreads();
        if (c + 3 < 129) GLOAD1(c + 3);
        if (c + 2 < 129) DSW0((s + 2) % 3);
        CMP((s + 1) % 3);
    }
    if (c < 129) { __syncthreads(); CMP(c % 3); }

    #pragma unroll
    for (int eg = 0; eg < 2; ++eg)
        #pragma unroll
        for (int r = 0; r < 4; ++r) {
            int e = e0 + eg * 16 + q * 4 + r;
            if (e < NE) {
                int d = dst[e];
                #pragma unroll
                for (int nt = 0; nt < 4; ++nt)
                    atomicAdd(&agg[(long)d * 64 + nt * 16 + m], msg[eg][nt][r]);
            }
        }
}

// =============== kgruz v2: vectorized GRU (f32x4 LDS + coalesced repacked weights) ===============
// Was LDS-issue bound (1024 scalar broadcast reads/thread). Now k-unrolled by 4:
// 256 f32x4 LDS reads + 96 coalesced f32x4 weight loads; relu folded into staging.
__global__ void kgruz(const float* __restrict__ agg, const float* __restrict__ h,
                      const float* __restrict__ wgxt, const float* __restrict__ bgx,
                      const float* __restrict__ wght, const float* __restrict__ bgh,
                      float* __restrict__ hof, unsigned short* __restrict__ hb,
                      float* __restrict__ aggN) {
    const int bid = blockIdx.x, tid = threadIdx.x;
    if (bid >= 625) {
        long base = (long)(bid - 625) * 2048 + tid;
        #pragma unroll
        for (int r = 0; r < 8; ++r) {
            long i = base + r * 256;
            if (i < 320000) reinterpret_cast<f32x4*>(aggN)[i] = f32x4{0.f, 0.f, 0.f, 0.f};
        }
        return;
    }
    __shared__ __align__(16) float sA[2048], sH[2048];
    const int n0 = bid * 32;
    const float* ab = agg + (long)n0 * 64;
    const float* hrow = h + (long)n0 * 64;
    for (int i = tid; i < 2048; i += 256) {
        sA[i] = fmaxf(ab[i], 0.f);      // relu folded into staging
        sH[i] = hrow[i];
    }
    __syncthreads();
    const int u = tid & 63, jg = tid >> 6;
    float xr[8], xz[8], xn[8], hr[8], hz[8], hn[8];
    float b0 = bgx[u], b1 = bgx[64 + u], b2 = bgx[128 + u];
    float d0 = bgh[u], d1 = bgh[64 + u], d2 = bgh[128 + u];
    #pragma unroll
    for (int j = 0; j < 8; ++j) {
        xr[j] = b0; xz[j] = b1; xn[j] = b2;
        hr[j] = d0; hz[j] = d1; hn[j] = d2;
    }
    const int u4 = u * 4;
    #pragma unroll 4
    for (int kb = 0; kb < 16; ++kb) {
        const float* wxb = wgxt + kb * 768;
        const float* whb = wght + kb * 768;
        f32x4 w0 = *reinterpret_cast<const f32x4*>(wxb + u4);
        f32x4 w1 = *reinterpret_cast<const f32x4*>(wxb + 256 + u4);
        f32x4 w2 = *reinterpret_cast<const f32x4*>(wxb + 512 + u4);
        f32x4 v0 = *reinterpret_cast<const f32x4*>(whb + u4);
        f32x4 v1 = *reinterpret_cast<const f32x4*>(whb + 256 + u4);
        f32x4 v2 = *reinterpret_cast<const f32x4*>(whb + 512 + u4);
        #pragma unroll
        for (int j = 0; j < 8; ++j) {
            int n = jg * 8 + j;
            f32x4 av = *reinterpret_cast<const f32x4*>(&sA[n * 64 + kb * 4]);
            f32x4 hv = *reinterpret_cast<const f32x4*>(&sH[n * 64 + kb * 4]);
            #pragma unroll
            for (int kk = 0; kk < 4; ++kk) {
                xr[j] += av[kk] * w0[kk];
                xz[j] += av[kk] * w1[kk];
                xn[j] += av[kk] * w2[kk];
                hr[j] += hv[kk] * v0[kk];
                hz[j] += hv[kk] * v1[kk];
                hn[j] += hv[kk] * v2[kk];
            }
        }
    }
    #pragma unroll
    for (int j = 0; j < 8; ++j) {
        int n = jg * 8 + j;
        float rg = sigm(xr[j] + hr[j]);
        float zg = sigm(xz[j] + hz[j]);
        float ng = tanhf(xn[j] + rg * hn[j]);
        long o = (long)(n0 + n) * 64 + u;
        float hv = (1.f - zg) * ng + zg * sH[n * 64 + u];
        hof[o] = hv;
        hb[o] = f2bf(hv);
    }
}

// =============== readout scatter: feat[dst] += [h[src] | relu(ef@Wep+bep)] ===============
__global__ void kreadout(const float* __restrict__ h,
                         const float* __restrict__ ef, const float* __restrict__ Wep,
                         const float* __restrict__ bep,
                         const int* __restrict__ src, const int* __restrict__ dst,
                         float* __restrict__ feat) {
    int t = blockIdx.x * blockDim.x + threadIdx.x;
    if (t >= NE * 128) return;
    int e = t >> 7, j = t & 127;
    float v;
    if (j < 64) {
        v = h[(long)src[e] * 64 + j];
    } else {
        int o = j - 64;
        v = bep[o];
        #pragma unroll
        for (int k = 0; k < 6; ++k) v += ef[(long)e * 6 + k] * Wep[k * 64 + o];
        v = fmaxf(v, 0.f);
    }
    atomicAdd(&feat[(long)dst[e] * 128 + j], v);
}

// =============== klstmattn v9 (R14): fused 6 iters, 2 graphs/block, feat cache, 4-lane score ===============
__global__ __launch_bounds__(512) void klstmattn(
    const float* __restrict__ feat, const int* __restrict__ seg,
    float* __restrict__ esg,
    const unsigned short* __restrict__ wb,
    const float* __restrict__ bl0, const float* __restrict__ bl1, const float* __restrict__ bl2,
    const float* __restrict__ fpb,
    const float* __restrict__ bf1, const float* __restrict__ bf2, const float* __restrict__ bp,
    float* __restrict__ out) {
    __shared__ float sQ[2][256];    // q_star (persistent across iterations)
    __shared__ float sHs[3][2][128];// LSTM h state per layer
    __shared__ float sCs[3][2][128];// LSTM c state per layer
    __shared__ float sG[2][512];    // gates
    __shared__ float sE[2][512];    // attention scores/exp; reused as comb(384) in head
    __shared__ float sH2[2][128];   // layer-2 h (q)
    __shared__ float sR[2][2][128]; // racc partials
    __shared__ float sred[2][4];
    __shared__ float s1b[2][300];
    __shared__ float s2[2][256];
    __shared__ __align__(16) float sF[2][CF * CFS]; // cached feat rows (padded stride)
#if HAVE_DOT2
    __shared__ __align__(16) unsigned int sXp[2][128];  // packed f16 layer-input x
    __shared__ __align__(16) unsigned int sHp[2][64];   // packed f16 recurrent h_in
#else
    __shared__ float sXH[2][256];   // layer input x (f32 fallback)
    __shared__ float sHin[2][128];  // recurrent h_in (f32 fallback)
#endif
    const int tid = threadIdx.x;
    const int b0g = blockIdx.x * 2;
    const unsigned short* Wx[3] = {wb + O_WX0, wb + O_WX1, wb + O_WX2};
    const unsigned short* Wh[3] = {wb + O_WH0, wb + O_WH1, wb + O_WH2};
    const float* bl[3] = {bl0, bl1, bl2};

    const int group = tid >> 8;         // 0..1 (attention/head indexing)
    const int t = tid & 255;
    const int wv = t >> 6, lane = t & 63;
    const int j = t & 127, half = t >> 7;
    const int s0 = seg[b0g + group], s1 = seg[b0g + group + 1], len = s1 - s0;

    // zero-init persistent state + cache feat rows (one barrier covers all)
    sQ[tid >> 8][tid & 255] = 0.f;
    {
        float* hp = &sHs[0][0][0];
        float* cp = &sCs[0][0][0];
        for (int i = tid; i < 768; i += 512) { hp[i] = 0.f; cp[i] = 0.f; }
    }
    {
        int rows = len < CF ? len : CF;
        for (int i = t; i < rows * 128; i += 256)
            sF[group][(i >> 7) * CFS + (i & 127)] = feat[(long)(s0 + (i >> 7)) * 128 + (i & 127)];
    }
    __syncthreads();

    for (int t6 = 0; t6 < 6; ++t6) {
        // stage x (q_star) and layer-0 h_in
#if HAVE_DOT2
        if (tid < 256) {
            int b = tid >> 7, u = tid & 127;
            sXp[b][u] = pack2f16(sQ[b][2 * u], sQ[b][2 * u + 1]);
        } else if (tid < 384) {
            int t2 = tid - 256;
            int bb = t2 >> 6, uu = t2 & 63;
            sHp[bb][uu] = pack2f16(sHs[0][bb][2 * uu], sHs[0][bb][2 * uu + 1]);
        }
#else
        {
            int b = tid >> 8, u = tid & 255;
            sXH[b][u] = sQ[b][u];
            if (tid < 256) {
                int bb = tid >> 7, uu = tid & 127;
                sHin[bb][uu] = sHs[0][bb][uu];
            }
        }
#endif
        __syncthreads();

        // ---- 3-layer LSTM ----
        for (int l = 0; l < 3; ++l) {
            const int Kx = l ? 128 : 256;
            const int g = tid;
            const unsigned short* wxp = Wx[l];
            const unsigned short* whp = Wh[l];
            float bv = bl[l][g];
            float a0 = bv, a1 = bv, a0b = 0.f, a1b = 0.f;
#if HAVE_DOT2
            #pragma unroll 8
            for (int kb = 0; kb < (Kx >> 3); ++kb) {
                u32x4 wu = *reinterpret_cast<const u32x4*>(wxp + ((kb << 9) + g) * 8);
                u32x4 x0 = *reinterpret_cast<const u32x4*>(&sXp[0][kb << 2]);
                u32x4 x1 = *reinterpret_cast<const u32x4*>(&sXp[1][kb << 2]);
                a0  = __builtin_amdgcn_fdot2(BC2(wu[0]), BC2(x0[0]), a0,  false);
                a1  = __builtin_amdgcn_fdot2(BC2(wu[0]), BC2(x1[0]), a1,  false);
                a0b = __builtin_amdgcn_fdot2(BC2(wu[1]), BC2(x0[1]), a0b, false);
                a1b = __builtin_amdgcn_fdot2(BC2(wu[1]), BC2(x1[1]), a1b, false);
                a0  = __builtin_amdgcn_fdot2(BC2(wu[2]), BC2(x0[2]), a0,  false);
                a1  = __builtin_amdgcn_fdot2(BC2(wu[2]), BC2(x1[2]), a1,  false);
                a0b = __builtin_amdgcn_fdot2(BC2(wu[3]), BC2(x0[3]), a0b, false);
                a1b = __builtin_amdgcn_fdot2(BC2(wu[3]), BC2(x1[3]), a1b, false);
            }
            #pragma unroll 8
            for (int kb = 0; kb < 16; ++kb) {
                u32x4 wu = *reinterpret_cast<const u32x4*>(whp + ((kb << 9) + g) * 8);
                u32x4 h0 = *reinterpret_cast<const u32x4*>(&sHp[0][kb << 2]);
                u32x4 h1 = *reinterpret_cast<const u32x4*>(&sHp[1][kb << 2]);
                a0  = __builtin_amdgcn_fdot2(BC2(wu[0]), BC2(h0[0]), a0,  false);
                a1  = __builtin_amdgcn_fdot2(BC2(wu[0]), BC2(h1[0]), a1,  false);
                a0b = __builtin_amdgcn_fdot2(BC2(wu[1]), BC2(h0[1]), a0b, false);
                a1b = __builtin_amdgcn_fdot2(BC2(wu[1]), BC2(h1[1]), a1b, false);
                a0  = __builtin_amdgcn_fdot2(BC2(wu[2]), BC2(h0[2]), a0,  false);
                a1  = __builtin_amdgcn_fdot2(BC2(wu[2]), BC2(h1[2]), a1,  false);
                a0b = __builtin_amdgcn_fdot2(BC2(wu[3]), BC2(h0[3]), a0b, false);
                a1b = __builtin_amdgcn_fdot2(BC2(wu[3]), BC2(h1[3]), a1b, false);
            }
#else
            #pragma unroll 8
            for (int kb = 0; kb < (Kx >> 3); ++kb) {
                short8 wvv = *reinterpret_cast<const short8*>(wxp + ((kb << 9) + g) * 8);
                const f32x4* xp0 = reinterpret_cast<const f32x4*>(&sXH[0][kb << 3]);
                const f32x4* xp1 = reinterpret_cast<const f32x4*>(&sXH[1][kb << 3]);
                f32x4 xa0 = xp0[0], xb0 = xp0[1];
                f32x4 xa1 = xp1[0], xb1 = xp1[1];
                #pragma unroll
                for (int kk = 0; kk < 4; ++kk) {
                    float w0 = w2f((unsigned short)wvv[kk]);
                    float w1 = w2f((unsigned short)wvv[kk + 4]);
                    a0  += xa0[kk] * w0;  a1  += xa1[kk] * w0;
                    a0b += xb0[kk] * w1;  a1b += xb1[kk] * w1;
                }
            }
            #pragma unroll 8
            for (int kb = 0; kb < 16; ++kb) {
                short8 wvv = *reinterpret_cast<const short8*>(whp + ((kb << 9) + g) * 8);
                const f32x4* hp0 = reinterpret_cast<const f32x4*>(&sHin[0][kb << 3]);
                const f32x4* hp1 = reinterpret_cast<const f32x4*>(&sHin[1][kb << 3]);
                f32x4 ha0 = hp0[0], hb0 = hp0[1];
                f32x4 ha1 = hp1[0], hb1 = hp1[1];
                #pragma unroll
                for (int kk = 0; kk < 4; ++kk) {
                    float w0 = w2f((unsigned short)wvv[kk]);
                    float w1 = w2f((unsigned short)wvv[kk + 4]);
                    a0  += ha0[kk] * w0;  a1  += ha1[kk] * w0;
                    a0b += hb0[kk] * w1;  a1b += hb1[kk] * w1;
                }
            }
#endif
            sG[0][g] = a0 + a0b;
            sG[1][g] = a1 + a1b;
            __syncthreads();
            if (tid < 256) {
                int b = tid >> 7, u = tid & 127;
                float gi = sG[b][u], gf = sG[b][128 + u], gg = sG[b][256 + u], go = sG[b][384 + u];
                float c_ = sigm(gf) * sCs[l][b][u] + sigm(gi) * tanhf(gg);
                float h_ = sigm(go) * tanhf(c_);
                sCs[l][b][u] = c_;
                sHs[l][b][u] = h_;
                if (l == 2) sH2[b][u] = h_;
#if HAVE_DOT2
                float hn = __shfl_down(h_, 1, 64);
                if (!(u & 1)) sXp[b][u >> 1] = pack2f16(h_, hn);
#else
                sXH[b][u] = h_;                 // next layer's x
#endif
            } else if (l < 2) {
                int t2 = tid - 256;
#if HAVE_DOT2
                if (t2 < 128) {
                    int bb = t2 >> 6, uu = t2 & 63;
                    sHp[bb][uu] = pack2f16(sHs[l + 1][bb][2 * uu], sHs[l + 1][bb][2 * uu + 1]);
                }
#else
                int b = t2 >> 7, u = t2 & 127;
                sHin[b][u] = sHs[l + 1][b][u];
#endif
            }
            __syncthreads();
        }

        // ---- attention (256 threads per graph) ----
        // score: 4 lanes per row, lane sums 32 dims, 2-level shfl_xor combine
        for (int base = wv * 16; base < len; base += 64) {
            int r = base + (lane >> 2);
            float p = 0.f;
            if (r < len) {
                const int d0 = (lane & 3) * 32;
                const float* qp = &sH2[group][d0];
                if (r < CF) {
                    const float* fp = &sF[group][r * CFS + d0];
                    #pragma unroll
                    for (int k = 0; k < 32; k += 4) {
                        f32x4 fv = *reinterpret_cast<const f32x4*>(fp + k);
                        p += fv[0] * qp[k] + fv[1] * qp[k + 1]
                           + fv[2] * qp[k + 2] + fv[3] * qp[k + 3];
                    }
                } else {
                    const float* fp = &feat[(long)(s0 + r) * 128 + d0];
                    #pragma unroll
                    for (int k = 0; k < 32; k += 4) {
                        f32x4 fv = *reinterpret_cast<const f32x4*>(fp + k);
                        p += fv[0] * qp[k] + fv[1] * qp[k + 1]
                           + fv[2] * qp[k + 2] + fv[3] * qp[k + 3];
                    }
                }
            }
            p += __shfl_xor(p, 1, 64);
            p += __shfl_xor(p, 2, 64);
            if ((lane & 3) == 0 && r < len) {
                if (r < 512) sE[group][r] = p; else esg[s0 + r] = p;
            }
        }
        __syncthreads();
        auto ev = [&](int i) { return i < 512 ? sE[group][i] : esg[s0 + i]; };
        float lm = -1e30f;
        for (int i = t; i < len; i += 256) lm = fmaxf(lm, ev(i));
        for (int off = 32; off; off >>= 1) lm = fmaxf(lm, __shfl_down(lm, off, 64));
        if (lane == 0) sred[group][wv] = lm;
        __syncthreads();
        float mx = fmaxf(fmaxf(sred[group][0], sred[group][1]),
                         fmaxf(sred[group][2], sred[group][3]));
        __syncthreads();
        float ls = 0.f;
        for (int i = t; i < len; i += 256) {
            float e_ = expf(ev(i) - mx);
            if (i < 512) sE[group][i] = e_; else esg[s0 + i] = e_;
            ls += e_;
        }
        for (int off = 32; off; off >>= 1) ls += __shfl_down(ls, off, 64);
        if (lane == 0) sred[group][wv] = ls;
        __syncthreads();
        float inv = 1.f / (sred[group][0] + sred[group][1] + sred[group][2] + sred[group][3] + 1e-9f);
        // racc with 2 independent accumulators (load ILP); feat from LDS cache when possible
        float r0 = 0.f, r1 = 0.f;
        {
            int i = half;
            for (; i + 2 < len; i += 4) {
                float fa = (i < CF) ? sF[group][i * CFS + j]
                                    : feat[(long)(s0 + i) * 128 + j];
                float fb = (i + 2 < CF) ? sF[group][(i + 2) * CFS + j]
                                        : feat[(long)(s0 + i + 2) * 128 + j];
                r0 += ev(i) * fa;
                r1 += ev(i + 2) * fb;
            }
            for (; i < len; i += 2) {
                float fa = (i < CF) ? sF[group][i * CFS + j]
                                    : feat[(long)(s0 + i) * 128 + j];
                r0 += ev(i) * fa;
            }
        }
        sR[group][half][j] = r0 + r1;
        __syncthreads();
        float rr = (sR[group][0][j] + sR[group][1][j]) * inv;
        if (half == 0) {
            sQ[group][j] = sH2[group][j];        // q
            sQ[group][128 + j] = rr;             // r
        }

        if (t6 == 5) {
            __syncthreads();
            // ---- FFN head: comb(384) -> 300 -> 256 -> NTASK ----
            if (half == 0) {
                sE[group][j] = sH2[group][j];
                sE[group][128 + j] = rr;
            } else {
                sE[group][256 + j] = fpb[(long)(b0g + group) * 128 + j];
            }
            __syncthreads();
            const unsigned short* Wf1b = wb + O_WF1;
            const unsigned short* Wf2b = wb + O_WF2;
            const unsigned short* Wpb  = wb + O_WP;
            for (int task = tid; task < 600; task += 512) {
                int g = task / 300, u = task % 300;
                float acc = bf1[u];
                for (int k = 0; k < 384; ++k) acc += sE[g][k] * w2f(Wf1b[k * 300 + u]);
                s1b[g][u] = fmaxf(acc, 0.f);
            }
            __syncthreads();
            for (int task = tid; task < 512; task += 512) {
                int g = task >> 8, u = task & 255;
                float acc = bf2[u];
                for (int k = 0; k < 300; ++k) acc += s1b[g][k] * w2f(Wf2b[k * 256 + u]);
                s2[g][u] = fmaxf(acc, 0.f);
            }
            __syncthreads();
            for (int task = tid; task < 2 * NTASK; task += 512) {
                int g = task / NTASK, u = task % NTASK;
                float acc = bp[u];
                for (int k = 0; k < 256; ++k) acc += s2[g][k] * w2f(Wpb[k * NTASK + u]);
                out[(long)(b0g + g) * NTASK + u] = acc;
            }
        } else {
            __syncthreads();   // protect sQ/sE reuse before next iteration
        }
    }
}

extern "C" void kernel_launch(void* const* d_in, const int* in_sizes, int n_in,
                              void* d_out, int out_size, void* d_ws, size_t ws_size,
                              hipStream_t stream) {
    auto fp_ = [&](int i) { return (const float*)d_in[i]; };
    auto ip_ = [&](int i) { return (const int*)d_in[i]; };
    const float *nf = fp_(0), *ef = fp_(1), *fpv = fp_(2);
    const int *src = ip_(3), *dst = ip_(4), *gid = ip_(5);
    const float *Wn = fp_(6), *bn = fp_(7), *We1 = fp_(8), *be1 = fp_(9);
    const float *We2 = fp_(10), *be2 = fp_(11), *Wres = fp_(12);
    const float *Wgx = fp_(13), *bgx = fp_(14), *Wgh = fp_(15), *bgh = fp_(16);
    const float *Wep = fp_(17), *bep = fp_(18);
    const float *Wlx0 = fp_(19), *Wlh0 = fp_(20), *bl0 = fp_(21);
    const float *Wlx1 = fp_(22), *Wlh1 = fp_(23), *bl1 = fp_(24);
    const float *Wlx2 = fp_(25), *Wlh2 = fp_(26), *bl2 = fp_(27);
    const float *Wfp = fp_(28), *bfpv = fp_(29);
    const float *bng = fp_(30), *bnb = fp_(31), *bnm = fp_(32), *bnv = fp_(33);
    const float *Wf1 = fp_(34), *bf1 = fp_(35), *Wf2 = fp_(36), *bf2 = fp_(37);
    const float *Wp = fp_(38), *bp = fp_(39);

    char* w = (char*)d_ws;
    auto alloc = [&](size_t bytes) -> char* {
        char* p = w; w += (bytes + 255) & ~(size_t)255; return p;
    };
    float* hA = (float*)alloc((size_t)NN * 64 * 4);
    float* hB = (float*)alloc((size_t)NN * 64 * 4);
    unsigned short* hbA = (unsigned short*)alloc((size_t)NN * 64 * 2);
    unsigned short* hbB = (unsigned short*)alloc((size_t)NN * 64 * 2);
    unsigned short* we2thi = (unsigned short*)alloc((size_t)129 * 4096 * 2);
    unsigned short* wbf = (unsigned short*)alloc((size_t)NWB * 2);
    float* wgxt = (float*)alloc((size_t)192 * 64 * 4);   // repacked GRU x-weights
    float* wght = (float*)alloc((size_t)192 * 64 * 4);   // repacked GRU h-weights
    float* aggB = (float*)alloc((size_t)NN * 64 * 4);   // zeroed by kgruz
    char* zstart = w;                               // ---- zeroed region start ----
    float* aggA  = (float*)alloc((size_t)NN * 64 * 4);
    float* feat  = (float*)alloc((size_t)NN * 128 * 4);
    size_t zfloats = (size_t)(w - zstart) / 4;      // ---- zeroed region end ----
    float* es   = (float*)alloc((size_t)NN * 4);
    int*   seg  = (int*)alloc((size_t)(NB + 1) * 4);
    float* fpb  = (float*)alloc((size_t)NB * 128 * 4);
    float* xt   = (float*)alloc((size_t)128 * EPAD * 4);   // X_T edge-net activations

    // --- kpre section boundaries ---
    int nz4 = (int)(zfloats / 4);
    int zb  = (nz4 + 2047) / 2048;
    int B0 = zb;
    int B1 = B0 + 129;            // we2T: 1 block/chunk
    int B2 = B1 + 4;              // seg
    int B3 = B2 + NB;             // fpenc: 1 block/graph
    int B4 = B3 + 1250;           // nodeproj: 16 nodes/block
    int B5 = B4 + 235;            // xprep: 256 edges/block
    int B6 = B5 + 2;              // gruT: 2 blocks
    int B7 = B6 + (NWB + 2047) / 2048;  // weight conversion
    kpre<<<B7, 256, 0, stream>>>((float*)zstart, nz4, We2, be2, we2thi, gid, seg,
                                 fpv, Wfp, bfpv, bng, bnb, bnm, bnv, fpb,
                                 nf, Wn, bn, hA, hbA,
                                 ef, We1, be1, xt,
                                 Wgx, Wgh, wgxt, wght,
                                 Wlx0, Wlh0, Wlx1, Wlh1, Wlx2, Wlh2, Wf1, Wf2, Wp, wbf,
                                 B0, B1, B2, B3, B4, B5, B6);

    float* hf[2] = {hA, hB};
    unsigned short* hb[2] = {hbA, hbB};
    float* aggbuf[2] = {aggA, aggB};
    int cur = 0;
    for (int it = 0; it < 3; ++it) {
        float* agg  = aggbuf[it & 1];
        float* aggN = aggbuf[1 - (it & 1)];
        keinsum<<<469 + 625, 256, 0, stream>>>(hb[cur], hf[cur], Wres,
                                               xt, we2thi, src, dst, agg);
        kgruz<<<625 + 157, 256, 0, stream>>>(agg, hf[cur], wgxt, bgx, wght, bgh,
                                             hf[1 - cur], hb[1 - cur], aggN);
        cur = 1 - cur;
    }
    kreadout<<<(NE * 128 + 255) / 256, 256, 0, stream>>>(hf[cur], ef, Wep, bep, src, dst, feat);

    klstmattn<<<NB / 2, 512, 0, stream>>>(feat, seg, es, wbf, bl0, bl1, bl2,
                                          fpb, bf1, bf2, bp, (float*)d_out);
}